// Round 12
// baseline (195.141 us; speedup 1.0000x reference)
//
#include <hip/hip_runtime.h>
#include <math.h>
#include <float.h>

#define B   256
#define D   256
#define D1  1024
#define D2  512
#define D3  256
#define NDIST (D1 + D2 + D3)   // 1792
#define CQ  2.0f               // qV2 static scale multiplier (step = sa[d]*CQ)

typedef __attribute__((ext_vector_type(8))) short short8;
typedef __attribute__((ext_vector_type(4))) float f32x4;
typedef __attribute__((ext_vector_type(4))) int   i32x4;

__device__ __forceinline__ float waveReduceSum(float v) {
    #pragma unroll
    for (int off = 32; off > 0; off >>= 1)
        v += __shfl_down(v, off, 64);
    return v;
}
__device__ __forceinline__ float waveReduceMax(float v) {
    #pragma unroll
    for (int off = 32; off > 0; off >>= 1)
        v = fmaxf(v, __shfl_down(v, off, 64));
    return v;
}
__device__ __forceinline__ unsigned short f2bf(float f) {
    unsigned int u = __float_as_uint(f);
    u = (u + 0x7FFFu + ((u >> 16) & 1u)) >> 16;   // RNE
    return (unsigned short)u;
}
__device__ __forceinline__ float bf2f(unsigned short h) {
    return __uint_as_float(((unsigned int)h) << 16);
}
__device__ __forceinline__ void gld16(const void* g, void* l) {
    __builtin_amdgcn_global_load_lds(
        (const __attribute__((address_space(1))) unsigned int*)g,
        (__attribute__((address_space(3))) unsigned int*)l, 16, 0, 0);
}
__device__ __forceinline__ int swz_src(int row, int lane) {
    return ((lane & 3) + ((row >> 1) & 3)) & 3;
}
__device__ __forceinline__ int swz_frag(int row, int quad) {
    return row * 32 + (((quad - ((row >> 1) & 3)) & 3) * 8);
}

// ---- mega prep: zero z2/z3/norms/out, hi/lo splits, i8 quants, rn1 ---------
__global__ __launch_bounds__(256) void k_prep(
    const float* __restrict__ x,  const float* __restrict__ W1,
    const float* __restrict__ W2, const float* __restrict__ W3,
    float* __restrict__ zeros,                 // z2||z3||norm2||norm3, 393216 f
    float* __restrict__ outp,
    unsigned short* __restrict__ xhi,  unsigned short* __restrict__ xlo,
    unsigned short* __restrict__ W1hi, unsigned short* __restrict__ W1lo,
    unsigned short* __restrict__ W2hi, unsigned short* __restrict__ W2lo,
    unsigned short* __restrict__ W3hi, unsigned short* __restrict__ W3lo,
    signed char* __restrict__ W1Ti8, float* __restrict__ saq,
    signed char* __restrict__ W2i8,  float* __restrict__ sbq,
    signed char* __restrict__ W3i8,  float* __restrict__ s3q,
    float* __restrict__ rn1) {
    int blk = blockIdx.x;
    int t = threadIdx.x;
    if (blk < 1536) {                                  // zero region (+ out)
        if (blk == 0 && t == 0) outp[0] = 0.f;
        zeros[blk * 256 + t] = 0.f;
        return;
    }
    if (blk < 2496) {                                  // hi/lo splits
        int i4 = ((blk - 1536) * 256 + t) * 4;
        const float* src; unsigned short *hi, *lo; int off;
        if (i4 < 65536)       { src = x;  hi = xhi;  lo = xlo;  off = i4; }
        else if (i4 < 327680) { src = W1; hi = W1hi; lo = W1lo; off = i4 - 65536; }
        else if (i4 < 851968) { src = W2; hi = W2hi; lo = W2lo; off = i4 - 327680; }
        else                  { src = W3; hi = W3hi; lo = W3lo; off = i4 - 851968; }
        float4 v = *(const float4*)(src + off);
        ushort4 h, l;
        h.x = f2bf(v.x); l.x = f2bf(v.x - bf2f(h.x));
        h.y = f2bf(v.y); l.y = f2bf(v.y - bf2f(h.y));
        h.z = f2bf(v.z); l.z = f2bf(v.z - bf2f(h.z));
        h.w = f2bf(v.w); l.w = f2bf(v.w - bf2f(h.w));
        *(ushort4*)(hi + off) = h;
        *(ushort4*)(lo + off) = l;
        return;
    }
    if (blk < 2528) {                                  // W1 col quant -> W1Ti8
        int ty = t >> 5, tx = t & 31;
        int d = (blk - 2496) * 8 + ty;
        float m = 0.f;
        for (int i = tx; i < D1; i += 32) m = fmaxf(m, fabsf(W1[(size_t)i * D + d]));
        #pragma unroll
        for (int off = 16; off > 0; off >>= 1) m = fmaxf(m, __shfl_down(m, off, 32));
        m = __shfl(m, 0, 32);
        m = fmaxf(m, 1e-20f);
        if (tx == 0) saq[d] = m / 127.f;
        float inv = 127.f / m;
        for (int i = tx; i < D1; i += 32) {
            int q = __float2int_rn(W1[(size_t)i * D + d] * inv);
            W1Ti8[(size_t)d * D1 + i] = (signed char)q;
        }
        return;
    }
    if (blk < 2656) {                                  // W2 row quant
        int o = (blk - 2528) * 4 + (t >> 6);
        int l = t & 63;
        const float* row = W2 + (size_t)o * D1;
        float m = 0.f;
        for (int tt = l; tt < D1; tt += 64) m = fmaxf(m, fabsf(row[tt]));
        m = waveReduceMax(m);
        m = __shfl(m, 0, 64);
        m = fmaxf(m, 1e-20f);
        if (l == 0) sbq[o] = m / 127.f;
        float inv = 127.f / m;
        for (int tt = l; tt < D1; tt += 64)
            W2i8[(size_t)o * D1 + tt] = (signed char)__float2int_rn(row[tt] * inv);
        return;
    }
    if (blk < 2720) {                                  // W3 row quant
        int p = (blk - 2656) * 4 + (t >> 6);
        int l = t & 63;
        const float* row = W3 + (size_t)p * D2;
        float m = 0.f;
        for (int tt = l; tt < D2; tt += 64) m = fmaxf(m, fabsf(row[tt]));
        m = waveReduceMax(m);
        m = __shfl(m, 0, 64);
        m = fmaxf(m, 1e-20f);
        if (l == 0) s3q[p] = m / 127.f;
        float inv = 127.f / m;
        for (int tt = l; tt < D2; tt += 64)
            W3i8[(size_t)p * D2 + tt] = (signed char)__float2int_rn(row[tt] * inv);
        return;
    }
    {                                                  // rn1 (W1 row norms)
        int gw = (blk - 2720) * 4 + (t >> 6);
        int lane = t & 63;
        const float* row = W1 + (size_t)gw * D;
        float s = 0.f;
        for (int tt = lane; tt < D; tt += 64) { float v = row[tt]; s += v * v; }
        s = waveReduceSum(s);
        if (lane == 0) rn1[gw] = sqrtf(s);
    }
}

// ---- compensated bf16 MFMA mainloop, 64x64 tile, K range [k0, k0+KL) -------
template <int KD, int KL>
__device__ __forceinline__ void mfma3_64(
    const unsigned short* __restrict__ Ahi, const unsigned short* __restrict__ Alo,
    const unsigned short* __restrict__ Bhi, const unsigned short* __restrict__ Blo,
    int m0, int n0, int k0, unsigned short* sm, f32x4 acc[2][2]) {
    int tid = threadIdx.x;
    int l = tid & 63, w = tid >> 6;
    int rsub = l >> 2;
    int quad = l >> 4, l16 = l & 15;
    int wm = (w >> 1) * 32, wn = (w & 1) * 32;
    unsigned short* sAh = sm;
    unsigned short* sAl = sm + 2048;
    unsigned short* sBh = sm + 4096;
    unsigned short* sBl = sm + 6144;
    ptrdiff_t dA = Alo - Ahi, dB = Blo - Bhi;
    int rloc = w * 16 + rsub;
    int c = swz_src(rloc, l);
    const unsigned short* pa = Ahi + (size_t)(m0 + rloc) * KD + k0 + c * 8;
    const unsigned short* pb = Bhi + (size_t)(n0 + rloc) * KD + k0 + c * 8;
    int aoff[2], boff[2];
    #pragma unroll
    for (int mt = 0; mt < 2; mt++) aoff[mt] = swz_frag(wm + mt * 16 + l16, quad);
    #pragma unroll
    for (int nt = 0; nt < 2; nt++) boff[nt] = swz_frag(wn + nt * 16 + l16, quad);
    for (int kk = 0; kk < KL; kk += 32) {
        gld16(pa + kk,      sAh + w * 512);
        gld16(pa + dA + kk, sAl + w * 512);
        gld16(pb + kk,      sBh + w * 512);
        gld16(pb + dB + kk, sBl + w * 512);
        __syncthreads();
        short8 ah[2], al[2], bh[2], bl[2];
        #pragma unroll
        for (int mt = 0; mt < 2; mt++) {
            ah[mt] = *(const short8*)(sAh + aoff[mt]);
            al[mt] = *(const short8*)(sAl + aoff[mt]);
        }
        #pragma unroll
        for (int nt = 0; nt < 2; nt++) {
            bh[nt] = *(const short8*)(sBh + boff[nt]);
            bl[nt] = *(const short8*)(sBl + boff[nt]);
        }
        #pragma unroll
        for (int mt = 0; mt < 2; mt++)
            #pragma unroll
            for (int nt = 0; nt < 2; nt++) {
                acc[mt][nt] = __builtin_amdgcn_mfma_f32_16x16x32_bf16(ah[mt], bh[nt], acc[mt][nt], 0, 0, 0);
                acc[mt][nt] = __builtin_amdgcn_mfma_f32_16x16x32_bf16(ah[mt], bl[nt], acc[mt][nt], 0, 0, 0);
                acc[mt][nt] = __builtin_amdgcn_mfma_f32_16x16x32_bf16(al[mt], bh[nt], acc[mt][nt], 0, 0, 0);
            }
        __syncthreads();
    }
}

// ---- layer 1: z1 -> dist1 (stride D1), m1q bytes, h1 hi/lo -----------------
__global__ __launch_bounds__(256) void k_l1(
    const unsigned short* __restrict__ xhi,  const unsigned short* __restrict__ xlo,
    const unsigned short* __restrict__ W1hi, const unsigned short* __restrict__ W1lo,
    const float* __restrict__ b1, const float* __restrict__ rn1,
    float* __restrict__ dists, unsigned char* __restrict__ m1q,
    unsigned short* __restrict__ h1hi, unsigned short* __restrict__ h1lo) {
    __shared__ __align__(16) unsigned short sm[8192];
    int m0 = blockIdx.x * 64, n0 = blockIdx.y * 64;
    f32x4 acc[2][2] = {};
    mfma3_64<D, D>(xhi, xlo, W1hi, W1lo, m0, n0, 0, sm, acc);
    int l = threadIdx.x & 63, w = threadIdx.x >> 6;
    int quad = l >> 4, l16 = l & 15;
    int wm = (w >> 1) * 32, wn = (w & 1) * 32;
    #pragma unroll
    for (int mt = 0; mt < 2; mt++)
        #pragma unroll
        for (int nt = 0; nt < 2; nt++) {
            int n = n0 + wn + nt * 16 + l16;
            float bv = b1[n], rv = rn1[n];
            #pragma unroll
            for (int r = 0; r < 4; r++) {
                int m = m0 + wm + mt * 16 + quad * 4 + r;
                float z = acc[mt][nt][r] + bv;
                size_t idx = (size_t)m * D1 + n;
                dists[idx] = fabsf(z) / rv;
                m1q[idx] = (z > 0.f) ? 0xFFu : 0u;
                float h = z > 0.f ? z : 0.f;
                unsigned short hh = f2bf(h);
                h1hi[idx] = hh;
                h1lo[idx] = f2bf(h - bf2f(hh));
            }
        }
}

// ---- merged dispatch 1: l2a (blocks 0..127) || gemm1 NB=2 (128..1151) ------
// gemm1 stages batch-independent W1T/W2 once per K-chunk, runs 2 batches'
// MFMA sets on it (masks differ) — staging/barrier per MFMA halved.
__global__ __launch_bounds__(256) void k_big1(
    const unsigned short* __restrict__ h1hi, const unsigned short* __restrict__ h1lo,
    const unsigned short* __restrict__ W2hi, const unsigned short* __restrict__ W2lo,
    float* __restrict__ z2,
    const signed char* __restrict__ W1Ti8,   // [256][1024]  A rows (d)
    const signed char* __restrict__ W2i8,    // [512][1024]  B rows (o)
    const unsigned char* __restrict__ m1q,   // [B][1024]
    const float* __restrict__ saq,           // [256]
    const float* __restrict__ sbq,           // [512]
    signed char* __restrict__ qV2,           // [256][256][512] (d-major)
    float* __restrict__ norm2) {             // [B][512]
    __shared__ __align__(16) unsigned char smem[32768];
    int bid = blockIdx.x;

    if (bid < 128) {
        // ---- l2a: split-K partial z2 (atomic) ----
        unsigned short* sm = (unsigned short*)smem;
        int m0 = (bid & 3) * 64, n0 = ((bid >> 2) & 7) * 64, k0 = (bid >> 5) * 256;
        f32x4 acc[2][2] = {};
        mfma3_64<D1, 256>(h1hi, h1lo, W2hi, W2lo, m0, n0, k0, sm, acc);
        int l = threadIdx.x & 63, w = threadIdx.x >> 6;
        int quad = l >> 4, l16 = l & 15;
        int wm = (w >> 1) * 32, wn = (w & 1) * 32;
        #pragma unroll
        for (int mt = 0; mt < 2; mt++)
            #pragma unroll
            for (int nt = 0; nt < 2; nt++) {
                int n = n0 + wn + nt * 16 + l16;
                #pragma unroll
                for (int r = 0; r < 4; r++) {
                    int m = m0 + wm + mt * 16 + quad * 4 + r;
                    atomicAdd(&z2[(size_t)m * D2 + n], acc[mt][nt][r]);
                }
            }
        return;
    }

    // ---- gemm1 (i8, BK=128, M=d/N=o, mask on A; 2 batches per block) ----
    int j = bid - 128;                // 0..1023
    signed char* As = (signed char*)smem;
    signed char* Bs = (signed char*)smem + 16384;
    int m0 = (j & 1) * 128;           // d
    int o0 = ((j >> 1) & 3) * 128;    // o
    int bp = j >> 3;                  // batch pair 0..127
    int tid = threadIdx.x;
    int l = tid & 63, w = tid >> 6;
    int quad = l >> 4, l16 = l & 15;
    int wm = (w >> 1) * 64, wn = (w & 1) * 64;
    const unsigned char* mrow0 = m1q + (size_t)(bp * 2) * D1;
    const unsigned char* mrow1 = m1q + (size_t)(bp * 2 + 1) * D1;

    const signed char* pa[4];
    const signed char* pb[4];
    int lrow = l >> 3, ls = l & 7;
    #pragma unroll
    for (int r = 0; r < 4; r++) {
        int row = r * 32 + w * 8 + lrow;
        int c = (ls + (row & 7)) & 7;
        pa[r] = W1Ti8 + (size_t)(m0 + row) * D1 + c * 16;
        pb[r] = W2i8 + (size_t)(o0 + row) * D1 + c * 16;
    }
    int aoff[4][2], boff[4][2];
    #pragma unroll
    for (int mt = 0; mt < 4; mt++) {
        int tr = wm + mt * 16 + l16;
        #pragma unroll
        for (int ks = 0; ks < 2; ks++)
            aoff[mt][ks] = tr * 128 + (((ks * 4 + quad) - (tr & 7)) & 7) * 16;
    }
    #pragma unroll
    for (int nt = 0; nt < 4; nt++) {
        int tr = wn + nt * 16 + l16;
        #pragma unroll
        for (int ks = 0; ks < 2; ks++)
            boff[nt][ks] = tr * 128 + (((ks * 4 + quad) - (tr & 7)) & 7) * 16;
    }

    i32x4 acc[2][4][4];
    #pragma unroll
    for (int bb = 0; bb < 2; bb++)
        #pragma unroll
        for (int i = 0; i < 4; i++)
            #pragma unroll
            for (int jj = 0; jj < 4; jj++) acc[bb][i][jj] = (i32x4)0;

    for (int kk = 0; kk < D1; kk += 128) {
        #pragma unroll
        for (int r = 0; r < 4; r++) {
            gld16(pa[r] + kk, As + r * 4096 + w * 1024);
            gld16(pb[r] + kk, Bs + r * 4096 + w * 1024);
        }
        i32x4 mA0 = *(const i32x4*)(mrow0 + kk + quad * 16);
        i32x4 mA1 = *(const i32x4*)(mrow0 + kk + 64 + quad * 16);
        i32x4 mB0 = *(const i32x4*)(mrow1 + kk + quad * 16);
        i32x4 mB1 = *(const i32x4*)(mrow1 + kk + 64 + quad * 16);
        __syncthreads();
        #pragma unroll
        for (int ks = 0; ks < 2; ks++) {
            i32x4 araw[4], bq[4];
            #pragma unroll
            for (int mt = 0; mt < 4; mt++)
                araw[mt] = *(const i32x4*)(As + aoff[mt][ks]);
            #pragma unroll
            for (int nt = 0; nt < 4; nt++)
                bq[nt] = *(const i32x4*)(Bs + boff[nt][ks]);
            i32x4 mv0 = ks ? mA1 : mA0;
            i32x4 mv1 = ks ? mB1 : mB0;
            #pragma unroll
            for (int mt = 0; mt < 4; mt++) {
                i32x4 a0 = araw[mt] & mv0;
                #pragma unroll
                for (int nt = 0; nt < 4; nt++)
                    acc[0][mt][nt] = __builtin_amdgcn_mfma_i32_16x16x64_i8(
                        a0, bq[nt], acc[0][mt][nt], 0, 0, 0);
            }
            #pragma unroll
            for (int mt = 0; mt < 4; mt++) {
                i32x4 a1 = araw[mt] & mv1;
                #pragma unroll
                for (int nt = 0; nt < 4; nt++)
                    acc[1][mt][nt] = __builtin_amdgcn_mfma_i32_16x16x64_i8(
                        a1, bq[nt], acc[1][mt][nt], 0, 0, 0);
            }
        }
        __syncthreads();
    }

    // batch-independent scales
    float sad[4][4];
    #pragma unroll
    for (int mt = 0; mt < 4; mt++)
        #pragma unroll
        for (int r = 0; r < 4; r++)
            sad[mt][r] = saq[m0 + wm + mt * 16 + quad * 4 + r];
    float sbv[4], sbdq[4];
    #pragma unroll
    for (int nt = 0; nt < 4; nt++) {
        sbv[nt] = sbq[o0 + wn + nt * 16 + l16];
        sbdq[nt] = sbv[nt] * (1.0f / CQ);
    }

    #pragma unroll
    for (int bb = 0; bb < 2; bb++) {
        int b = bp * 2 + bb;
        #pragma unroll
        for (int nt = 0; nt < 4; nt++) {
            float s = 0.f;
            #pragma unroll
            for (int mt = 0; mt < 4; mt++)
                #pragma unroll
                for (int r = 0; r < 4; r++) {
                    float v = (float)acc[bb][mt][nt][r] * sad[mt][r] * sbv[nt];
                    s += v * v;
                }
            s += __shfl_down(s, 32, 64);
            s += __shfl_down(s, 16, 64);
            if (l < 16)
                atomicAdd(&norm2[(size_t)b * D2 + o0 + wn + nt * 16 + l], s);
        }
        signed char* qb = qV2 + (size_t)b * (D * D2);
        #pragma unroll
        for (int mt = 0; mt < 4; mt++) {
            int dbase = m0 + wm + mt * 16 + quad * 4;
            #pragma unroll
            for (int r = 0; r < 4; r++)
                #pragma unroll
                for (int nt = 0; nt < 4; nt++) {
                    int o = o0 + wn + nt * 16 + l16;
                    int qi = __float2int_rn((float)acc[bb][mt][nt][r] * sbdq[nt]);
                    qi = max(-127, min(127, qi));
                    qb[(size_t)(dbase + r) * D2 + o] = (signed char)qi;
                }
        }
    }
}

// ---- layer 2 phase B: bias + m2q + h2 hi/lo --------------------------------
__global__ __launch_bounds__(256) void k_l2b(
    const float* __restrict__ b2, float* __restrict__ z2,
    unsigned char* __restrict__ m2q,
    unsigned short* __restrict__ h2hi, unsigned short* __restrict__ h2lo) {
    int idx = blockIdx.x * 256 + threadIdx.x;     // B*D2
    int n = idx & (D2 - 1);
    float z = z2[idx] + b2[n];
    z2[idx] = z;
    m2q[idx] = (z > 0.f) ? 0xFFu : 0u;
    float h = z > 0.f ? z : 0.f;
    unsigned short hh = f2bf(h);
    h2hi[idx] = hh;
    h2lo[idx] = f2bf(h - bf2f(hh));
}

// ---- merged dispatch 2: l3a (blocks 0..31) || gemm2 d-paired (32..543) -----
// gemm2 pairs the two d-tiles of one batch: A (W3) staged once, shared mask,
// norm3 combined across tiles before the atomic.
__global__ __launch_bounds__(256) void k_big2(
    const unsigned short* __restrict__ h2hi, const unsigned short* __restrict__ h2lo,
    const unsigned short* __restrict__ W3hi, const unsigned short* __restrict__ W3lo,
    float* __restrict__ z3,
    const signed char* __restrict__ W3i8,    // [256][512]
    const signed char* __restrict__ qV2,     // [256][256][512]
    const unsigned char* __restrict__ m2q,   // [B][512]
    const float* __restrict__ saq,           // [256]
    const float* __restrict__ s3q,           // [256]
    float* __restrict__ norm3) {             // [B][256]
    __shared__ __align__(16) unsigned char smem[49152];   // As 16K + Bs0 16K + Bs1 16K
    int bid = blockIdx.x;

    if (bid < 32) {
        // ---- l3a: split-K partial z3 (atomic; bias folded into topk) ----
        unsigned short* sm = (unsigned short*)smem;
        int m0 = (bid & 3) * 64, n0 = ((bid >> 2) & 3) * 64, k0 = (bid >> 4) * 256;
        f32x4 acc[2][2] = {};
        mfma3_64<D2, 256>(h2hi, h2lo, W3hi, W3lo, m0, n0, k0, sm, acc);
        int l = threadIdx.x & 63, w = threadIdx.x >> 6;
        int quad = l >> 4, l16 = l & 15;
        int wm = (w >> 1) * 32, wn = (w & 1) * 32;
        #pragma unroll
        for (int mt = 0; mt < 2; mt++)
            #pragma unroll
            for (int nt = 0; nt < 2; nt++) {
                int n = n0 + wn + nt * 16 + l16;
                #pragma unroll
                for (int r = 0; r < 4; r++) {
                    int m = m0 + wm + mt * 16 + quad * 4 + r;
                    atomicAdd(&z3[(size_t)m * D3 + n], acc[mt][nt][r]);
                }
            }
        return;
    }

    // ---- gemm2 (i8, BK=128): both d-tiles of one batch ----
    int j = bid - 32;                 // 0..511
    signed char* As  = (signed char*)smem;
    signed char* Bs0 = (signed char*)smem + 16384;
    signed char* Bs1 = (signed char*)smem + 32768;
    int m0 = (j & 1) * 128;           // p
    int bc = j >> 1;                  // batch
    int tid = threadIdx.x;
    int l = tid & 63, w = tid >> 6;
    int quad = l >> 4, l16 = l & 15;
    int wm = (w >> 1) * 64, wn = (w & 1) * 64;
    const unsigned char* mrow = m2q + (size_t)bc * D2;
    const signed char* Bsrc = qV2 + (size_t)bc * (D * D2);

    const signed char* pa[4];
    const signed char* pb0[4];
    const signed char* pb1[4];
    int lrow = l >> 3, ls = l & 7;
    #pragma unroll
    for (int r = 0; r < 4; r++) {
        int row = r * 32 + w * 8 + lrow;
        int c = (ls + (row & 7)) & 7;
        pa[r]  = W3i8 + (size_t)(m0 + row) * D2 + c * 16;
        pb0[r] = Bsrc + (size_t)row * D2 + c * 16;
        pb1[r] = Bsrc + (size_t)(128 + row) * D2 + c * 16;
    }
    int aoff[4][2], boff[4][2];
    #pragma unroll
    for (int mt = 0; mt < 4; mt++) {
        int tr = wm + mt * 16 + l16;
        #pragma unroll
        for (int ks = 0; ks < 2; ks++)
            aoff[mt][ks] = tr * 128 + (((ks * 4 + quad) - (tr & 7)) & 7) * 16;
    }
    #pragma unroll
    for (int nt = 0; nt < 4; nt++) {
        int tr = wn + nt * 16 + l16;
        #pragma unroll
        for (int ks = 0; ks < 2; ks++)
            boff[nt][ks] = tr * 128 + (((ks * 4 + quad) - (tr & 7)) & 7) * 16;
    }

    i32x4 acc[2][4][4];
    #pragma unroll
    for (int dd = 0; dd < 2; dd++)
        #pragma unroll
        for (int i = 0; i < 4; i++)
            #pragma unroll
            for (int jj = 0; jj < 4; jj++) acc[dd][i][jj] = (i32x4)0;

    for (int kk = 0; kk < D2; kk += 128) {
        #pragma unroll
        for (int r = 0; r < 4; r++) {
            gld16(pa[r] + kk,  As  + r * 4096 + w * 1024);
            gld16(pb0[r] + kk, Bs0 + r * 4096 + w * 1024);
            gld16(pb1[r] + kk, Bs1 + r * 4096 + w * 1024);
        }
        i32x4 mv0 = *(const i32x4*)(mrow + kk + quad * 16);
        i32x4 mv1 = *(const i32x4*)(mrow + kk + 64 + quad * 16);
        __syncthreads();
        #pragma unroll
        for (int ks = 0; ks < 2; ks++) {
            i32x4 mv = ks ? mv1 : mv0;
            i32x4 a[4];
            #pragma unroll
            for (int mt = 0; mt < 4; mt++)
                a[mt] = *(const i32x4*)(As + aoff[mt][ks]);
            #pragma unroll
            for (int nt = 0; nt < 4; nt++) {
                i32x4 b0 = (*(const i32x4*)(Bs0 + boff[nt][ks])) & mv;
                #pragma unroll
                for (int mt = 0; mt < 4; mt++)
                    acc[0][mt][nt] = __builtin_amdgcn_mfma_i32_16x16x64_i8(
                        a[mt], b0, acc[0][mt][nt], 0, 0, 0);
            }
            #pragma unroll
            for (int nt = 0; nt < 4; nt++) {
                i32x4 b1 = (*(const i32x4*)(Bs1 + boff[nt][ks])) & mv;
                #pragma unroll
                for (int mt = 0; mt < 4; mt++)
                    acc[1][mt][nt] = __builtin_amdgcn_mfma_i32_16x16x64_i8(
                        a[mt], b1, acc[1][mt][nt], 0, 0, 0);
            }
        }
        __syncthreads();
    }

    float saCQ0[4], saCQ1[4];
    #pragma unroll
    for (int nt = 0; nt < 4; nt++) {
        saCQ0[nt] = saq[wn + nt * 16 + l16] * CQ;
        saCQ1[nt] = saq[128 + wn + nt * 16 + l16] * CQ;
    }

    #pragma unroll
    for (int mt = 0; mt < 4; mt++)
        #pragma unroll
        for (int r = 0; r < 4; r++) {
            float s = 0.f;
            #pragma unroll
            for (int nt = 0; nt < 4; nt++) {
                float v0 = (float)acc[0][mt][nt][r] * saCQ0[nt];
                float v1 = (float)acc[1][mt][nt][r] * saCQ1[nt];
                s += v0 * v0 + v1 * v1;
            }
            s += __shfl_down(s, 8, 64);
            s += __shfl_down(s, 4, 64);
            s += __shfl_down(s, 2, 64);
            s += __shfl_down(s, 1, 64);
            if (l16 == 0) {
                int p = m0 + wm + mt * 16 + quad * 4 + r;
                float s3 = s3q[p];
                atomicAdd(&norm3[(size_t)bc * D3 + p], s * s3 * s3);
            }
        }
}

// ---- per-batch k-smallest sum; dist2/dist3 + z3 bias inline ----------------
__global__ __launch_bounds__(256) void k_topk(
    const float* __restrict__ dists,    // [B][D1] dist1 only
    const float* __restrict__ z2, const float* __restrict__ norm2,
    const float* __restrict__ z3, const float* __restrict__ b3,
    const float* __restrict__ norm3,
    const int* __restrict__ kp, float* __restrict__ outp) {
    __shared__ unsigned long long wmin[4];
    int b = blockIdx.x, t = threadIdx.x;
    float lv[7];
    #pragma unroll
    for (int j = 0; j < 4; j++) lv[j] = dists[(size_t)b * D1 + t + 256 * j];
    #pragma unroll
    for (int j = 4; j < 6; j++) {
        int o = t + 256 * j - 1024;
        lv[j] = fabsf(z2[(size_t)b * D2 + o]) / sqrtf(norm2[(size_t)b * D2 + o]);
    }
    {
        float zz = z3[(size_t)b * D3 + t] + b3[t];
        lv[6] = fabsf(zz) / sqrtf(norm3[(size_t)b * D3 + t]);
    }
    int k = *kp;
    if (k > NDIST) k = NDIST;
    float sum = 0.f;
    for (int it = 0; it < k; it++) {
        float mv = lv[0]; int mj = 0;
        #pragma unroll
        for (int j = 1; j < 7; j++)
            if (lv[j] < mv) { mv = lv[j]; mj = j; }
        unsigned long long key =
            ((unsigned long long)__float_as_uint(mv) << 32) | (unsigned)(t * 8 + mj);
        #pragma unroll
        for (int off = 32; off > 0; off >>= 1) {
            unsigned long long o = __shfl_down(key, off, 64);
            if (o < key) key = o;
        }
        if ((t & 63) == 0) wmin[t >> 6] = key;
        __syncthreads();
        unsigned long long k0 = wmin[0];
        #pragma unroll
        for (int ww = 1; ww < 4; ww++) if (wmin[ww] < k0) k0 = wmin[ww];
        sum += __uint_as_float((unsigned)(k0 >> 32));
        int wt = (int)((k0 & 0xFFFu) >> 3), wj = (int)(k0 & 7u);
        if (t == wt) lv[wj] = FLT_MAX;
        __syncthreads();
    }
    if (t == 0) atomicAdd(outp, sum);
}

extern "C" void kernel_launch(void* const* d_in, const int* in_sizes, int n_in,
                              void* d_out, int out_size, void* d_ws, size_t ws_size,
                              hipStream_t stream) {
    const float* x  = (const float*)d_in[0];
    const float* W1 = (const float*)d_in[1];
    const float* b1 = (const float*)d_in[2];
    const float* W2 = (const float*)d_in[3];
    const float* b2 = (const float*)d_in[4];
    const float* W3 = (const float*)d_in[5];
    const float* b3 = (const float*)d_in[6];
    const int*   kp = (const int*)d_in[7];
    float* outp = (float*)d_out;

    float* fp = (float*)d_ws;
    float* rn1     = fp;                          fp += D1;
    float* dists   = fp;                          fp += (size_t)B * D1;
    float* saq     = fp;                          fp += D;
    float* sbq     = fp;                          fp += D2;
    float* s3q     = fp;                          fp += D3;
    // zero region: z2 || z3 || norm2 || norm3 (contiguous, 393216 floats)
    float* z2      = fp;                          fp += (size_t)B * D2;
    float* z3      = fp;                          fp += (size_t)B * D3;
    float* norm2   = fp;                          fp += (size_t)B * D2;
    float* norm3   = fp;                          fp += (size_t)B * D3;
    unsigned short* up = (unsigned short*)fp;
    unsigned short* W2hi  = up;  up += (size_t)D2 * D1;
    unsigned short* W2lo  = up;  up += (size_t)D2 * D1;
    unsigned short* W3hi  = up;  up += (size_t)D3 * D2;
    unsigned short* W3lo  = up;  up += (size_t)D3 * D2;
    unsigned short* xhi   = up;  up += (size_t)B * D;
    unsigned short* xlo   = up;  up += (size_t)B * D;
    unsigned short* W1hi  = up;  up += (size_t)D1 * D;
    unsigned short* W1lo  = up;  up += (size_t)D1 * D;
    unsigned short* h1hi  = up;  up += (size_t)B * D1;
    unsigned short* h1lo  = up;  up += (size_t)B * D1;
    unsigned short* h2hi  = up;  up += (size_t)B * D2;
    unsigned short* h2lo  = up;  up += (size_t)B * D2;
    signed char*    cp = (signed char*)up;
    signed char*    W1Ti8 = cp;  cp += (size_t)D * D1;
    signed char*    W2i8  = cp;  cp += (size_t)D2 * D1;
    signed char*    W3i8  = cp;  cp += (size_t)D3 * D2;
    unsigned char*  m1q   = (unsigned char*)cp;  cp += (size_t)B * D1;
    unsigned char*  m2q   = (unsigned char*)cp;  cp += (size_t)B * D2;
    signed char*    qV2   = cp;   // full 256-batch (33.5 MB; ws proven since R10)

    k_prep<<<2976, 256, 0, stream>>>(x, W1, W2, W3, z2, outp,
                                     xhi, xlo, W1hi, W1lo, W2hi, W2lo, W3hi, W3lo,
                                     W1Ti8, saq, W2i8, sbq, W3i8, s3q, rn1);

    k_l1<<<dim3(B / 64, D1 / 64), 256, 0, stream>>>(xhi, xlo, W1hi, W1lo, b1, rn1,
                                                    dists, m1q, h1hi, h1lo);

    // l2a (128) || gemm1 NB=2 (1024)
    k_big1<<<1152, 256, 0, stream>>>(h1hi, h1lo, W2hi, W2lo, z2,
                                     W1Ti8, W2i8, m1q, saq, sbq, qV2, norm2);

    k_l2b<<<(B * D2) / 256, 256, 0, stream>>>(b2, z2, m2q, h2hi, h2lo);

    // l3a (32) || gemm2 d-paired (512)
    k_big2<<<544, 256, 0, stream>>>(h2hi, h2lo, W3hi, W3lo, z3,
                                    W3i8, qV2, m2q, saq, s3q, norm3);

    k_topk<<<B, 256, 0, stream>>>(dists, z2, norm2, z3, b3, norm3, kp, outp);
}

// Round 13
// 181.204 us; speedup vs baseline: 1.0769x; 1.0769x over previous
//
#include <hip/hip_runtime.h>
#include <math.h>
#include <float.h>

#define B   256
#define D   256
#define D1  1024
#define D2  512
#define D3  256
#define NDIST (D1 + D2 + D3)   // 1792
#define CQ  2.0f               // qV2 static scale multiplier (step = sa[d]*CQ)

typedef __attribute__((ext_vector_type(8))) short short8;
typedef __attribute__((ext_vector_type(4))) float f32x4;
typedef __attribute__((ext_vector_type(4))) int   i32x4;

__device__ __forceinline__ float waveReduceSum(float v) {
    #pragma unroll
    for (int off = 32; off > 0; off >>= 1)
        v += __shfl_down(v, off, 64);
    return v;
}
__device__ __forceinline__ float waveReduceMax(float v) {
    #pragma unroll
    for (int off = 32; off > 0; off >>= 1)
        v = fmaxf(v, __shfl_down(v, off, 64));
    return v;
}
__device__ __forceinline__ unsigned short f2bf(float f) {
    unsigned int u = __float_as_uint(f);
    u = (u + 0x7FFFu + ((u >> 16) & 1u)) >> 16;   // RNE
    return (unsigned short)u;
}
__device__ __forceinline__ float bf2f(unsigned short h) {
    return __uint_as_float(((unsigned int)h) << 16);
}
__device__ __forceinline__ void gld16(const void* g, void* l) {
    __builtin_amdgcn_global_load_lds(
        (const __attribute__((address_space(1))) unsigned int*)g,
        (__attribute__((address_space(3))) unsigned int*)l, 16, 0, 0);
}
__device__ __forceinline__ int swz_src(int row, int lane) {
    return ((lane & 3) + ((row >> 1) & 3)) & 3;
}
__device__ __forceinline__ int swz_frag(int row, int quad) {
    return row * 32 + (((quad - ((row >> 1) & 3)) & 3) * 8);
}

// ---- mega prep: zero z2/z3/norms/out, hi/lo splits, i8 quants, rn1 ---------
__global__ __launch_bounds__(256) void k_prep(
    const float* __restrict__ x,  const float* __restrict__ W1,
    const float* __restrict__ W2, const float* __restrict__ W3,
    float* __restrict__ zeros,                 // z2||z3||norm2||norm3, 393216 f
    float* __restrict__ outp,
    unsigned short* __restrict__ xhi,  unsigned short* __restrict__ xlo,
    unsigned short* __restrict__ W1hi, unsigned short* __restrict__ W1lo,
    unsigned short* __restrict__ W2hi, unsigned short* __restrict__ W2lo,
    unsigned short* __restrict__ W3hi, unsigned short* __restrict__ W3lo,
    signed char* __restrict__ W1Ti8, float* __restrict__ saq,
    signed char* __restrict__ W2i8,  float* __restrict__ sbq,
    signed char* __restrict__ W3i8,  float* __restrict__ s3q,
    float* __restrict__ rn1) {
    int blk = blockIdx.x;
    int t = threadIdx.x;
    if (blk < 1536) {                                  // zero region (+ out)
        if (blk == 0 && t == 0) outp[0] = 0.f;
        zeros[blk * 256 + t] = 0.f;
        return;
    }
    if (blk < 2496) {                                  // hi/lo splits
        int i4 = ((blk - 1536) * 256 + t) * 4;
        const float* src; unsigned short *hi, *lo; int off;
        if (i4 < 65536)       { src = x;  hi = xhi;  lo = xlo;  off = i4; }
        else if (i4 < 327680) { src = W1; hi = W1hi; lo = W1lo; off = i4 - 65536; }
        else if (i4 < 851968) { src = W2; hi = W2hi; lo = W2lo; off = i4 - 327680; }
        else                  { src = W3; hi = W3hi; lo = W3lo; off = i4 - 851968; }
        float4 v = *(const float4*)(src + off);
        ushort4 h, l;
        h.x = f2bf(v.x); l.x = f2bf(v.x - bf2f(h.x));
        h.y = f2bf(v.y); l.y = f2bf(v.y - bf2f(h.y));
        h.z = f2bf(v.z); l.z = f2bf(v.z - bf2f(h.z));
        h.w = f2bf(v.w); l.w = f2bf(v.w - bf2f(h.w));
        *(ushort4*)(hi + off) = h;
        *(ushort4*)(lo + off) = l;
        return;
    }
    if (blk < 2528) {                                  // W1 col quant -> W1Ti8
        int ty = t >> 5, tx = t & 31;
        int d = (blk - 2496) * 8 + ty;
        float m = 0.f;
        for (int i = tx; i < D1; i += 32) m = fmaxf(m, fabsf(W1[(size_t)i * D + d]));
        #pragma unroll
        for (int off = 16; off > 0; off >>= 1) m = fmaxf(m, __shfl_down(m, off, 32));
        m = __shfl(m, 0, 32);
        m = fmaxf(m, 1e-20f);
        if (tx == 0) saq[d] = m / 127.f;
        float inv = 127.f / m;
        for (int i = tx; i < D1; i += 32) {
            int q = __float2int_rn(W1[(size_t)i * D + d] * inv);
            W1Ti8[(size_t)d * D1 + i] = (signed char)q;
        }
        return;
    }
    if (blk < 2656) {                                  // W2 row quant
        int o = (blk - 2528) * 4 + (t >> 6);
        int l = t & 63;
        const float* row = W2 + (size_t)o * D1;
        float m = 0.f;
        for (int tt = l; tt < D1; tt += 64) m = fmaxf(m, fabsf(row[tt]));
        m = waveReduceMax(m);
        m = __shfl(m, 0, 64);
        m = fmaxf(m, 1e-20f);
        if (l == 0) sbq[o] = m / 127.f;
        float inv = 127.f / m;
        for (int tt = l; tt < D1; tt += 64)
            W2i8[(size_t)o * D1 + tt] = (signed char)__float2int_rn(row[tt] * inv);
        return;
    }
    if (blk < 2720) {                                  // W3 row quant
        int p = (blk - 2656) * 4 + (t >> 6);
        int l = t & 63;
        const float* row = W3 + (size_t)p * D2;
        float m = 0.f;
        for (int tt = l; tt < D2; tt += 64) m = fmaxf(m, fabsf(row[tt]));
        m = waveReduceMax(m);
        m = __shfl(m, 0, 64);
        m = fmaxf(m, 1e-20f);
        if (l == 0) s3q[p] = m / 127.f;
        float inv = 127.f / m;
        for (int tt = l; tt < D2; tt += 64)
            W3i8[(size_t)p * D2 + tt] = (signed char)__float2int_rn(row[tt] * inv);
        return;
    }
    {                                                  // rn1 (W1 row norms)
        int gw = (blk - 2720) * 4 + (t >> 6);
        int lane = t & 63;
        const float* row = W1 + (size_t)gw * D;
        float s = 0.f;
        for (int tt = lane; tt < D; tt += 64) { float v = row[tt]; s += v * v; }
        s = waveReduceSum(s);
        if (lane == 0) rn1[gw] = sqrtf(s);
    }
}

// ---- compensated bf16 MFMA mainloop, 64x64 tile, K range [k0, k0+KL) -------
template <int KD, int KL>
__device__ __forceinline__ void mfma3_64(
    const unsigned short* __restrict__ Ahi, const unsigned short* __restrict__ Alo,
    const unsigned short* __restrict__ Bhi, const unsigned short* __restrict__ Blo,
    int m0, int n0, int k0, unsigned short* sm, f32x4 acc[2][2]) {
    int tid = threadIdx.x;
    int l = tid & 63, w = tid >> 6;
    int rsub = l >> 2;
    int quad = l >> 4, l16 = l & 15;
    int wm = (w >> 1) * 32, wn = (w & 1) * 32;
    unsigned short* sAh = sm;
    unsigned short* sAl = sm + 2048;
    unsigned short* sBh = sm + 4096;
    unsigned short* sBl = sm + 6144;
    ptrdiff_t dA = Alo - Ahi, dB = Blo - Bhi;
    int rloc = w * 16 + rsub;
    int c = swz_src(rloc, l);
    const unsigned short* pa = Ahi + (size_t)(m0 + rloc) * KD + k0 + c * 8;
    const unsigned short* pb = Bhi + (size_t)(n0 + rloc) * KD + k0 + c * 8;
    int aoff[2], boff[2];
    #pragma unroll
    for (int mt = 0; mt < 2; mt++) aoff[mt] = swz_frag(wm + mt * 16 + l16, quad);
    #pragma unroll
    for (int nt = 0; nt < 2; nt++) boff[nt] = swz_frag(wn + nt * 16 + l16, quad);
    for (int kk = 0; kk < KL; kk += 32) {
        gld16(pa + kk,      sAh + w * 512);
        gld16(pa + dA + kk, sAl + w * 512);
        gld16(pb + kk,      sBh + w * 512);
        gld16(pb + dB + kk, sBl + w * 512);
        __syncthreads();
        short8 ah[2], al[2], bh[2], bl[2];
        #pragma unroll
        for (int mt = 0; mt < 2; mt++) {
            ah[mt] = *(const short8*)(sAh + aoff[mt]);
            al[mt] = *(const short8*)(sAl + aoff[mt]);
        }
        #pragma unroll
        for (int nt = 0; nt < 2; nt++) {
            bh[nt] = *(const short8*)(sBh + boff[nt]);
            bl[nt] = *(const short8*)(sBl + boff[nt]);
        }
        #pragma unroll
        for (int mt = 0; mt < 2; mt++)
            #pragma unroll
            for (int nt = 0; nt < 2; nt++) {
                acc[mt][nt] = __builtin_amdgcn_mfma_f32_16x16x32_bf16(ah[mt], bh[nt], acc[mt][nt], 0, 0, 0);
                acc[mt][nt] = __builtin_amdgcn_mfma_f32_16x16x32_bf16(ah[mt], bl[nt], acc[mt][nt], 0, 0, 0);
                acc[mt][nt] = __builtin_amdgcn_mfma_f32_16x16x32_bf16(al[mt], bh[nt], acc[mt][nt], 0, 0, 0);
            }
        __syncthreads();
    }
}

// ---- layer 1: z1 -> dist1 (stride D1), m1q bytes, h1 hi/lo -----------------
__global__ __launch_bounds__(256) void k_l1(
    const unsigned short* __restrict__ xhi,  const unsigned short* __restrict__ xlo,
    const unsigned short* __restrict__ W1hi, const unsigned short* __restrict__ W1lo,
    const float* __restrict__ b1, const float* __restrict__ rn1,
    float* __restrict__ dists, unsigned char* __restrict__ m1q,
    unsigned short* __restrict__ h1hi, unsigned short* __restrict__ h1lo) {
    __shared__ __align__(16) unsigned short sm[8192];
    int m0 = blockIdx.x * 64, n0 = blockIdx.y * 64;
    f32x4 acc[2][2] = {};
    mfma3_64<D, D>(xhi, xlo, W1hi, W1lo, m0, n0, 0, sm, acc);
    int l = threadIdx.x & 63, w = threadIdx.x >> 6;
    int quad = l >> 4, l16 = l & 15;
    int wm = (w >> 1) * 32, wn = (w & 1) * 32;
    #pragma unroll
    for (int mt = 0; mt < 2; mt++)
        #pragma unroll
        for (int nt = 0; nt < 2; nt++) {
            int n = n0 + wn + nt * 16 + l16;
            float bv = b1[n], rv = rn1[n];
            #pragma unroll
            for (int r = 0; r < 4; r++) {
                int m = m0 + wm + mt * 16 + quad * 4 + r;
                float z = acc[mt][nt][r] + bv;
                size_t idx = (size_t)m * D1 + n;
                dists[idx] = fabsf(z) / rv;
                m1q[idx] = (z > 0.f) ? 0xFFu : 0u;
                float h = z > 0.f ? z : 0.f;
                unsigned short hh = f2bf(h);
                h1hi[idx] = hh;
                h1lo[idx] = f2bf(h - bf2f(hh));
            }
        }
}

// ---- merged dispatch 1: l2a (blocks 0..127) || gemm1 (128..2175) -----------
__global__ __launch_bounds__(256) void k_big1(
    const unsigned short* __restrict__ h1hi, const unsigned short* __restrict__ h1lo,
    const unsigned short* __restrict__ W2hi, const unsigned short* __restrict__ W2lo,
    float* __restrict__ z2,
    const signed char* __restrict__ W1Ti8,   // [256][1024]  A rows (d)
    const signed char* __restrict__ W2i8,    // [512][1024]  B rows (o)
    const unsigned char* __restrict__ m1q,   // [B][1024]
    const float* __restrict__ saq,           // [256]
    const float* __restrict__ sbq,           // [512]
    signed char* __restrict__ qV2,           // [256][256][512] (d-major)
    float* __restrict__ norm2) {             // [B][512]
    __shared__ __align__(16) unsigned char smem[32768];
    int bid = blockIdx.x;

    if (bid < 128) {
        // ---- l2a: split-K partial z2 (atomic; bias folded downstream) ----
        unsigned short* sm = (unsigned short*)smem;
        int m0 = (bid & 3) * 64, n0 = ((bid >> 2) & 7) * 64, k0 = (bid >> 5) * 256;
        f32x4 acc[2][2] = {};
        mfma3_64<D1, 256>(h1hi, h1lo, W2hi, W2lo, m0, n0, k0, sm, acc);
        int l = threadIdx.x & 63, w = threadIdx.x >> 6;
        int quad = l >> 4, l16 = l & 15;
        int wm = (w >> 1) * 32, wn = (w & 1) * 32;
        #pragma unroll
        for (int mt = 0; mt < 2; mt++)
            #pragma unroll
            for (int nt = 0; nt < 2; nt++) {
                int n = n0 + wn + nt * 16 + l16;
                #pragma unroll
                for (int r = 0; r < 4; r++) {
                    int m = m0 + wm + mt * 16 + quad * 4 + r;
                    atomicAdd(&z2[(size_t)m * D2 + n], acc[mt][nt][r]);
                }
            }
        return;
    }

    // ---- gemm1 (i8, BK=128, M=d/N=o, mask on A) ----
    int j = bid - 128;
    signed char* As = (signed char*)smem;
    signed char* Bs = (signed char*)smem + 16384;
    int m0 = (j & 1) * 128;           // d
    int o0 = ((j >> 1) & 3) * 128;    // o
    int b = j >> 3;                   // batch
    int tid = threadIdx.x;
    int l = tid & 63, w = tid >> 6;
    int quad = l >> 4, l16 = l & 15;
    int wm = (w >> 1) * 64, wn = (w & 1) * 64;
    const unsigned char* mrow = m1q + (size_t)b * D1;

    const signed char* pa[4];
    const signed char* pb[4];
    int lrow = l >> 3, ls = l & 7;
    #pragma unroll
    for (int r = 0; r < 4; r++) {
        int row = r * 32 + w * 8 + lrow;
        int c = (ls + (row & 7)) & 7;
        pa[r] = W1Ti8 + (size_t)(m0 + row) * D1 + c * 16;
        pb[r] = W2i8 + (size_t)(o0 + row) * D1 + c * 16;
    }
    int aoff[4][2], boff[4][2];
    #pragma unroll
    for (int mt = 0; mt < 4; mt++) {
        int tr = wm + mt * 16 + l16;
        #pragma unroll
        for (int ks = 0; ks < 2; ks++)
            aoff[mt][ks] = tr * 128 + (((ks * 4 + quad) - (tr & 7)) & 7) * 16;
    }
    #pragma unroll
    for (int nt = 0; nt < 4; nt++) {
        int tr = wn + nt * 16 + l16;
        #pragma unroll
        for (int ks = 0; ks < 2; ks++)
            boff[nt][ks] = tr * 128 + (((ks * 4 + quad) - (tr & 7)) & 7) * 16;
    }

    i32x4 acc[4][4];
    #pragma unroll
    for (int i = 0; i < 4; i++)
        #pragma unroll
        for (int jj = 0; jj < 4; jj++) acc[i][jj] = (i32x4)0;

    for (int kk = 0; kk < D1; kk += 128) {
        #pragma unroll
        for (int r = 0; r < 4; r++) {
            gld16(pa[r] + kk, As + r * 4096 + w * 1024);
            gld16(pb[r] + kk, Bs + r * 4096 + w * 1024);
        }
        i32x4 mv0 = *(const i32x4*)(mrow + kk + quad * 16);
        i32x4 mv1 = *(const i32x4*)(mrow + kk + 64 + quad * 16);
        __syncthreads();
        #pragma unroll
        for (int ks = 0; ks < 2; ks++) {
            i32x4 mv = ks ? mv1 : mv0;
            i32x4 a[4], bq[4];
            #pragma unroll
            for (int mt = 0; mt < 4; mt++)
                a[mt] = (*(const i32x4*)(As + aoff[mt][ks])) & mv;
            #pragma unroll
            for (int nt = 0; nt < 4; nt++)
                bq[nt] = *(const i32x4*)(Bs + boff[nt][ks]);
            #pragma unroll
            for (int mt = 0; mt < 4; mt++)
                #pragma unroll
                for (int nt = 0; nt < 4; nt++)
                    acc[mt][nt] = __builtin_amdgcn_mfma_i32_16x16x64_i8(
                        a[mt], bq[nt], acc[mt][nt], 0, 0, 0);
        }
        __syncthreads();
    }

    float sad[4][4];
    #pragma unroll
    for (int mt = 0; mt < 4; mt++)
        #pragma unroll
        for (int r = 0; r < 4; r++)
            sad[mt][r] = saq[m0 + wm + mt * 16 + quad * 4 + r];
    float sbv[4], sbdq[4];
    #pragma unroll
    for (int nt = 0; nt < 4; nt++) {
        sbv[nt] = sbq[o0 + wn + nt * 16 + l16];
        sbdq[nt] = sbv[nt] * (1.0f / CQ);
    }

    // norm2[o] += sum_d V2^2
    #pragma unroll
    for (int nt = 0; nt < 4; nt++) {
        float s = 0.f;
        #pragma unroll
        for (int mt = 0; mt < 4; mt++)
            #pragma unroll
            for (int r = 0; r < 4; r++) {
                float v = (float)acc[mt][nt][r] * sad[mt][r] * sbv[nt];
                s += v * v;
            }
        s += __shfl_down(s, 32, 64);
        s += __shfl_down(s, 16, 64);
        if (l < 16)
            atomicAdd(&norm2[(size_t)b * D2 + o0 + wn + nt * 16 + l], s);
    }

    // qV2 epilogue: pack into LDS tile [128][144] then coalesced dwordx4 stores
    unsigned char* qt = (unsigned char*)smem;   // As/Bs dead after loop barrier
    #pragma unroll
    for (int mt = 0; mt < 4; mt++) {
        int dl = wm + mt * 16 + quad * 4;
        #pragma unroll
        for (int r = 0; r < 4; r++)
            #pragma unroll
            for (int nt = 0; nt < 4; nt++) {
                int ol = wn + nt * 16 + l16;
                int qi = __float2int_rn((float)acc[mt][nt][r] * sbdq[nt]);
                qi = max(-127, min(127, qi));
                qt[(dl + r) * 144 + ol] = (unsigned char)(signed char)qi;
            }
    }
    __syncthreads();
    signed char* qb = qV2 + (size_t)b * (D * D2);
    int row = tid >> 1, half = tid & 1;
    const unsigned char* srcp = qt + row * 144 + half * 64;
    signed char* dstp = qb + (size_t)(m0 + row) * D2 + o0 + half * 64;
    #pragma unroll
    for (int jj = 0; jj < 4; jj++)
        *(uint4*)(dstp + jj * 16) = *(const uint4*)(srcp + jj * 16);
}

// ---- merged dispatch 2: l3a z2-direct (0..31) || gemm2 (32..1055) ----------
// l2b eliminated: gemm2 derives m2 from z2+b2 into LDS; l3a computes h2 from
// z2+b2 during A-staging; topk adds b2/b3 inline.
__global__ __launch_bounds__(256) void k_big2(
    const float* __restrict__ z2,            // [B][512] (bias NOT applied)
    const float* __restrict__ b2,            // [512]
    const unsigned short* __restrict__ W3hi, const unsigned short* __restrict__ W3lo,
    float* __restrict__ z3,
    const signed char* __restrict__ W3i8,    // [256][512]
    const signed char* __restrict__ qV2,     // [256][256][512]
    const float* __restrict__ saq,           // [256]
    const float* __restrict__ s3q,           // [256]
    float* __restrict__ norm3) {             // [B][256]
    __shared__ __align__(16) unsigned char smem[33280];  // 32K tiles + 512B mask
    int bid = blockIdx.x;
    int tid = threadIdx.x;

    if (bid < 32) {
        // ---- l3a: split-K partial z3; A = relu(z2+b2) hi/lo computed inline
        unsigned short* sAh = (unsigned short*)smem;
        unsigned short* sAl = sAh + 2048;
        unsigned short* sBh = sAh + 4096;
        unsigned short* sBl = sAh + 6144;
        int m0 = (bid & 3) * 64, n0 = ((bid >> 2) & 3) * 64, k0 = (bid >> 4) * 256;
        int l = tid & 63, w = tid >> 6;
        int rsub = l >> 2;
        int quad = l >> 4, l16 = l & 15;
        int wm = (w >> 1) * 32, wn = (w & 1) * 32;
        int rloc = w * 16 + rsub;
        int c = swz_src(rloc, l);
        const float* pz  = z2 + (size_t)(m0 + rloc) * D2 + k0 + c * 8;
        const float* pbi = b2 + k0 + c * 8;
        const unsigned short* pb = W3hi + (size_t)(n0 + rloc) * D2 + k0 + c * 8;
        ptrdiff_t dB = W3lo - W3hi;
        int aoff[2], boff[2];
        #pragma unroll
        for (int mt = 0; mt < 2; mt++) aoff[mt] = swz_frag(wm + mt * 16 + l16, quad);
        #pragma unroll
        for (int nt = 0; nt < 2; nt++) boff[nt] = swz_frag(wn + nt * 16 + l16, quad);
        int wrA = w * 512 + l * 8;
        f32x4 acc[2][2] = {};
        for (int kk = 0; kk < 256; kk += 32) {
            gld16(pb + kk,      sBh + w * 512);
            gld16(pb + dB + kk, sBl + w * 512);
            float4 za = *(const float4*)(pz + kk);
            float4 zb = *(const float4*)(pz + kk + 4);
            float4 ba = *(const float4*)(pbi + kk);
            float4 bb = *(const float4*)(pbi + kk + 4);
            float hv[8] = { za.x + ba.x, za.y + ba.y, za.z + ba.z, za.w + ba.w,
                            zb.x + bb.x, zb.y + bb.y, zb.z + bb.z, zb.w + bb.w };
            short8 h8, l8;
            #pragma unroll
            for (int q2 = 0; q2 < 8; q2++) {
                float h = hv[q2] > 0.f ? hv[q2] : 0.f;
                unsigned short hh = f2bf(h);
                h8[q2] = (short)hh;
                l8[q2] = (short)f2bf(h - bf2f(hh));
            }
            *(short8*)(sAh + wrA) = h8;
            *(short8*)(sAl + wrA) = l8;
            __syncthreads();
            short8 ah[2], al[2], bh[2], bl[2];
            #pragma unroll
            for (int mt = 0; mt < 2; mt++) {
                ah[mt] = *(const short8*)(sAh + aoff[mt]);
                al[mt] = *(const short8*)(sAl + aoff[mt]);
            }
            #pragma unroll
            for (int nt = 0; nt < 2; nt++) {
                bh[nt] = *(const short8*)(sBh + boff[nt]);
                bl[nt] = *(const short8*)(sBl + boff[nt]);
            }
            #pragma unroll
            for (int mt = 0; mt < 2; mt++)
                #pragma unroll
                for (int nt = 0; nt < 2; nt++) {
                    acc[mt][nt] = __builtin_amdgcn_mfma_f32_16x16x32_bf16(ah[mt], bh[nt], acc[mt][nt], 0, 0, 0);
                    acc[mt][nt] = __builtin_amdgcn_mfma_f32_16x16x32_bf16(ah[mt], bl[nt], acc[mt][nt], 0, 0, 0);
                    acc[mt][nt] = __builtin_amdgcn_mfma_f32_16x16x32_bf16(al[mt], bh[nt], acc[mt][nt], 0, 0, 0);
                }
            __syncthreads();
        }
        #pragma unroll
        for (int mt = 0; mt < 2; mt++)
            #pragma unroll
            for (int nt = 0; nt < 2; nt++) {
                int n = n0 + wn + nt * 16 + l16;
                #pragma unroll
                for (int r = 0; r < 4; r++) {
                    int m = m0 + wm + mt * 16 + quad * 4 + r;
                    atomicAdd(&z3[(size_t)m * D3 + n], acc[mt][nt][r]);
                }
            }
        return;
    }

    // ---- gemm2 (i8, BK=128): norm3; m2 mask from z2+b2 in LDS ----
    int j = bid - 32;
    signed char* As = (signed char*)smem;
    signed char* Bs = (signed char*)smem + 16384;
    unsigned char* mbuf = (unsigned char*)smem + 32768;  // 512 B
    int m0 = (j & 1) * 128;           // p
    int n0 = ((j >> 1) & 1) * 128;    // d
    int bc = j >> 2;                  // batch
    int l = tid & 63, w = tid >> 6;
    int quad = l >> 4, l16 = l & 15;
    int wm = (w >> 1) * 64, wn = (w & 1) * 64;
    const signed char* Bsrc = qV2 + (size_t)bc * (D * D2);

    {   // fill m2 mask row for this batch
        #pragma unroll
        for (int rr = 0; rr < 2; rr++) {
            int o = tid * 2 + rr;
            float z = z2[(size_t)bc * D2 + o] + b2[o];
            mbuf[o] = (z > 0.f) ? 0xFFu : 0u;
        }
    }
    __syncthreads();

    const signed char* pa[4];
    const signed char* pb[4];
    int lrow = l >> 3, ls = l & 7;
    #pragma unroll
    for (int r = 0; r < 4; r++) {
        int row = r * 32 + w * 8 + lrow;
        int c = (ls + (row & 7)) & 7;
        pa[r] = W3i8 + (size_t)(m0 + row) * D2 + c * 16;
        pb[r] = Bsrc + (size_t)(n0 + row) * D2 + c * 16;
    }
    int aoff[4][2], boff[4][2];
    #pragma unroll
    for (int mt = 0; mt < 4; mt++) {
        int tr = wm + mt * 16 + l16;
        #pragma unroll
        for (int ks = 0; ks < 2; ks++)
            aoff[mt][ks] = tr * 128 + (((ks * 4 + quad) - (tr & 7)) & 7) * 16;
    }
    #pragma unroll
    for (int nt = 0; nt < 4; nt++) {
        int tr = wn + nt * 16 + l16;
        #pragma unroll
        for (int ks = 0; ks < 2; ks++)
            boff[nt][ks] = tr * 128 + (((ks * 4 + quad) - (tr & 7)) & 7) * 16;
    }

    i32x4 acc[4][4];
    #pragma unroll
    for (int i = 0; i < 4; i++)
        #pragma unroll
        for (int jj = 0; jj < 4; jj++) acc[i][jj] = (i32x4)0;

    for (int kk = 0; kk < D2; kk += 128) {
        #pragma unroll
        for (int r = 0; r < 4; r++) {
            gld16(pa[r] + kk, As + r * 4096 + w * 1024);
            gld16(pb[r] + kk, Bs + r * 4096 + w * 1024);
        }
        __syncthreads();
        i32x4 mv0 = *(const i32x4*)(mbuf + kk + quad * 16);
        i32x4 mv1 = *(const i32x4*)(mbuf + kk + 64 + quad * 16);
        #pragma unroll
        for (int ks = 0; ks < 2; ks++) {
            i32x4 mv = ks ? mv1 : mv0;
            i32x4 a[4], bq[4];
            #pragma unroll
            for (int mt = 0; mt < 4; mt++)
                a[mt] = *(const i32x4*)(As + aoff[mt][ks]);
            #pragma unroll
            for (int nt = 0; nt < 4; nt++)
                bq[nt] = (*(const i32x4*)(Bs + boff[nt][ks])) & mv;
            #pragma unroll
            for (int mt = 0; mt < 4; mt++)
                #pragma unroll
                for (int nt = 0; nt < 4; nt++)
                    acc[mt][nt] = __builtin_amdgcn_mfma_i32_16x16x64_i8(
                        a[mt], bq[nt], acc[mt][nt], 0, 0, 0);
        }
        __syncthreads();
    }

    float saCQ[4];
    #pragma unroll
    for (int nt = 0; nt < 4; nt++)
        saCQ[nt] = saq[n0 + wn + nt * 16 + l16] * CQ;

    #pragma unroll
    for (int mt = 0; mt < 4; mt++)
        #pragma unroll
        for (int r = 0; r < 4; r++) {
            float s = 0.f;
            #pragma unroll
            for (int nt = 0; nt < 4; nt++) {
                float v = (float)acc[mt][nt][r] * saCQ[nt];
                s += v * v;
            }
            s += __shfl_down(s, 8, 64);
            s += __shfl_down(s, 4, 64);
            s += __shfl_down(s, 2, 64);
            s += __shfl_down(s, 1, 64);
            if (l16 == 0) {
                int p = m0 + wm + mt * 16 + quad * 4 + r;
                float s3 = s3q[p];
                atomicAdd(&norm3[(size_t)bc * D3 + p], s * s3 * s3);
            }
        }
}

// ---- per-batch k-smallest sum; dist2/dist3 + biases inline -----------------
__global__ __launch_bounds__(256) void k_topk(
    const float* __restrict__ dists,    // [B][D1] dist1 only
    const float* __restrict__ z2, const float* __restrict__ b2,
    const float* __restrict__ norm2,
    const float* __restrict__ z3, const float* __restrict__ b3,
    const float* __restrict__ norm3,
    const int* __restrict__ kp, float* __restrict__ outp) {
    __shared__ unsigned long long wmin[4];
    int b = blockIdx.x, t = threadIdx.x;
    float lv[7];
    #pragma unroll
    for (int j = 0; j < 4; j++) lv[j] = dists[(size_t)b * D1 + t + 256 * j];
    #pragma unroll
    for (int j = 4; j < 6; j++) {
        int o = t + 256 * j - 1024;
        float zz = z2[(size_t)b * D2 + o] + b2[o];
        lv[j] = fabsf(zz) / sqrtf(norm2[(size_t)b * D2 + o]);
    }
    {
        float zz = z3[(size_t)b * D3 + t] + b3[t];
        lv[6] = fabsf(zz) / sqrtf(norm3[(size_t)b * D3 + t]);
    }
    int k = *kp;
    if (k > NDIST) k = NDIST;
    float sum = 0.f;
    for (int it = 0; it < k; it++) {
        float mv = lv[0]; int mj = 0;
        #pragma unroll
        for (int j = 1; j < 7; j++)
            if (lv[j] < mv) { mv = lv[j]; mj = j; }
        unsigned long long key =
            ((unsigned long long)__float_as_uint(mv) << 32) | (unsigned)(t * 8 + mj);
        #pragma unroll
        for (int off = 32; off > 0; off >>= 1) {
            unsigned long long o = __shfl_down(key, off, 64);
            if (o < key) key = o;
        }
        if ((t & 63) == 0) wmin[t >> 6] = key;
        __syncthreads();
        unsigned long long k0 = wmin[0];
        #pragma unroll
        for (int ww = 1; ww < 4; ww++) if (wmin[ww] < k0) k0 = wmin[ww];
        sum += __uint_as_float((unsigned)(k0 >> 32));
        int wt = (int)((k0 & 0xFFFu) >> 3), wj = (int)(k0 & 7u);
        if (t == wt) lv[wj] = FLT_MAX;
        __syncthreads();
    }
    if (t == 0) atomicAdd(outp, sum);
}

extern "C" void kernel_launch(void* const* d_in, const int* in_sizes, int n_in,
                              void* d_out, int out_size, void* d_ws, size_t ws_size,
                              hipStream_t stream) {
    const float* x  = (const float*)d_in[0];
    const float* W1 = (const float*)d_in[1];
    const float* b1 = (const float*)d_in[2];
    const float* W2 = (const float*)d_in[3];
    const float* b2 = (const float*)d_in[4];
    const float* W3 = (const float*)d_in[5];
    const float* b3 = (const float*)d_in[6];
    const int*   kp = (const int*)d_in[7];
    float* outp = (float*)d_out;

    float* fp = (float*)d_ws;
    float* rn1     = fp;                          fp += D1;
    float* dists   = fp;                          fp += (size_t)B * D1;
    float* saq     = fp;                          fp += D;
    float* sbq     = fp;                          fp += D2;
    float* s3q     = fp;                          fp += D3;
    // zero region: z2 || z3 || norm2 || norm3 (contiguous, 393216 floats)
    float* z2      = fp;                          fp += (size_t)B * D2;
    float* z3      = fp;                          fp += (size_t)B * D3;
    float* norm2   = fp;                          fp += (size_t)B * D2;
    float* norm3   = fp;                          fp += (size_t)B * D3;
    unsigned short* up = (unsigned short*)fp;
    unsigned short* W2hi  = up;  up += (size_t)D2 * D1;
    unsigned short* W2lo  = up;  up += (size_t)D2 * D1;
    unsigned short* W3hi  = up;  up += (size_t)D3 * D2;
    unsigned short* W3lo  = up;  up += (size_t)D3 * D2;
    unsigned short* xhi   = up;  up += (size_t)B * D;
    unsigned short* xlo   = up;  up += (size_t)B * D;
    unsigned short* W1hi  = up;  up += (size_t)D1 * D;
    unsigned short* W1lo  = up;  up += (size_t)D1 * D;
    unsigned short* h1hi  = up;  up += (size_t)B * D1;
    unsigned short* h1lo  = up;  up += (size_t)B * D1;
    signed char*    cp = (signed char*)up;
    signed char*    W1Ti8 = cp;  cp += (size_t)D * D1;
    signed char*    W2i8  = cp;  cp += (size_t)D2 * D1;
    signed char*    W3i8  = cp;  cp += (size_t)D3 * D2;
    unsigned char*  m1q   = (unsigned char*)cp;  cp += (size_t)B * D1;
    signed char*    qV2   = cp;   // full 256-batch (33.5 MB; ws proven since R10)

    k_prep<<<2976, 256, 0, stream>>>(x, W1, W2, W3, z2, outp,
                                     xhi, xlo, W1hi, W1lo, W2hi, W2lo, W3hi, W3lo,
                                     W1Ti8, saq, W2i8, sbq, W3i8, s3q, rn1);

    k_l1<<<dim3(B / 64, D1 / 64), 256, 0, stream>>>(xhi, xlo, W1hi, W1lo, b1, rn1,
                                                    dists, m1q, h1hi, h1lo);

    // l2a (128) || gemm1 (2048)
    k_big1<<<2176, 256, 0, stream>>>(h1hi, h1lo, W2hi, W2lo, z2,
                                     W1Ti8, W2i8, m1q, saq, sbq, qV2, norm2);

    // l3a z2-direct (32) || gemm2 mask-from-LDS (1024)
    k_big2<<<1056, 256, 0, stream>>>(z2, b2, W3hi, W3lo, z3,
                                     W3i8, qV2, saq, s3q, norm3);

    k_topk<<<B, 256, 0, stream>>>(dists, z2, b2, norm2, z3, b3, norm3, kp, outp);
}

// Round 14
// 181.189 us; speedup vs baseline: 1.0770x; 1.0001x over previous
//
#include <hip/hip_runtime.h>
#include <math.h>
#include <float.h>

#define B   256
#define D   256
#define D1  1024
#define D2  512
#define D3  256
#define NDIST (D1 + D2 + D3)   // 1792
#define CQ  2.0f               // qV2 static scale multiplier (step = sa[d]*CQ)

typedef __attribute__((ext_vector_type(8))) short short8;
typedef __attribute__((ext_vector_type(4))) float f32x4;
typedef __attribute__((ext_vector_type(4))) int   i32x4;

__device__ __forceinline__ float waveReduceSum(float v) {
    #pragma unroll
    for (int off = 32; off > 0; off >>= 1)
        v += __shfl_down(v, off, 64);
    return v;
}
__device__ __forceinline__ float waveReduceMax(float v) {
    #pragma unroll
    for (int off = 32; off > 0; off >>= 1)
        v = fmaxf(v, __shfl_down(v, off, 64));
    return v;
}
__device__ __forceinline__ unsigned short f2bf(float f) {
    unsigned int u = __float_as_uint(f);
    u = (u + 0x7FFFu + ((u >> 16) & 1u)) >> 16;   // RNE
    return (unsigned short)u;
}
__device__ __forceinline__ float bf2f(unsigned short h) {
    return __uint_as_float(((unsigned int)h) << 16);
}
__device__ __forceinline__ void gld16(const void* g, void* l) {
    __builtin_amdgcn_global_load_lds(
        (const __attribute__((address_space(1))) unsigned int*)g,
        (__attribute__((address_space(3))) unsigned int*)l, 16, 0, 0);
}
__device__ __forceinline__ int swz_src(int row, int lane) {
    return ((lane & 3) + ((row >> 1) & 3)) & 3;
}
__device__ __forceinline__ int swz_frag(int row, int quad) {
    return row * 32 + (((quad - ((row >> 1) & 3)) & 3) * 8);
}

// ---- mega prep: zero z2/z3/norms/out, hi/lo splits, i8 quants, rn1 ---------
__global__ __launch_bounds__(256) void k_prep(
    const float* __restrict__ x,  const float* __restrict__ W1,
    const float* __restrict__ W2, const float* __restrict__ W3,
    float* __restrict__ zeros,                 // z2||z3||norm2||norm3, 393216 f
    float* __restrict__ outp,
    unsigned short* __restrict__ xhi,  unsigned short* __restrict__ xlo,
    unsigned short* __restrict__ W1hi, unsigned short* __restrict__ W1lo,
    unsigned short* __restrict__ W2hi, unsigned short* __restrict__ W2lo,
    unsigned short* __restrict__ W3hi, unsigned short* __restrict__ W3lo,
    signed char* __restrict__ W1Ti8, float* __restrict__ saq,
    signed char* __restrict__ W2i8,  float* __restrict__ sbq,
    signed char* __restrict__ W3i8,  float* __restrict__ s3q,
    float* __restrict__ rn1) {
    int blk = blockIdx.x;
    int t = threadIdx.x;
    if (blk < 1536) {                                  // zero region (+ out)
        if (blk == 0 && t == 0) outp[0] = 0.f;
        zeros[blk * 256 + t] = 0.f;
        return;
    }
    if (blk < 2496) {                                  // hi/lo splits
        int i4 = ((blk - 1536) * 256 + t) * 4;
        const float* src; unsigned short *hi, *lo; int off;
        if (i4 < 65536)       { src = x;  hi = xhi;  lo = xlo;  off = i4; }
        else if (i4 < 327680) { src = W1; hi = W1hi; lo = W1lo; off = i4 - 65536; }
        else if (i4 < 851968) { src = W2; hi = W2hi; lo = W2lo; off = i4 - 327680; }
        else                  { src = W3; hi = W3hi; lo = W3lo; off = i4 - 851968; }
        float4 v = *(const float4*)(src + off);
        ushort4 h, l;
        h.x = f2bf(v.x); l.x = f2bf(v.x - bf2f(h.x));
        h.y = f2bf(v.y); l.y = f2bf(v.y - bf2f(h.y));
        h.z = f2bf(v.z); l.z = f2bf(v.z - bf2f(h.z));
        h.w = f2bf(v.w); l.w = f2bf(v.w - bf2f(h.w));
        *(ushort4*)(hi + off) = h;
        *(ushort4*)(lo + off) = l;
        return;
    }
    if (blk < 2528) {                                  // W1 col quant -> W1Ti8
        int ty = t >> 5, tx = t & 31;
        int d = (blk - 2496) * 8 + ty;
        float m = 0.f;
        for (int i = tx; i < D1; i += 32) m = fmaxf(m, fabsf(W1[(size_t)i * D + d]));
        #pragma unroll
        for (int off = 16; off > 0; off >>= 1) m = fmaxf(m, __shfl_down(m, off, 32));
        m = __shfl(m, 0, 32);
        m = fmaxf(m, 1e-20f);
        if (tx == 0) saq[d] = m / 127.f;
        float inv = 127.f / m;
        for (int i = tx; i < D1; i += 32) {
            int q = __float2int_rn(W1[(size_t)i * D + d] * inv);
            W1Ti8[(size_t)d * D1 + i] = (signed char)q;
        }
        return;
    }
    if (blk < 2656) {                                  // W2 row quant
        int o = (blk - 2528) * 4 + (t >> 6);
        int l = t & 63;
        const float* row = W2 + (size_t)o * D1;
        float m = 0.f;
        for (int tt = l; tt < D1; tt += 64) m = fmaxf(m, fabsf(row[tt]));
        m = waveReduceMax(m);
        m = __shfl(m, 0, 64);
        m = fmaxf(m, 1e-20f);
        if (l == 0) sbq[o] = m / 127.f;
        float inv = 127.f / m;
        for (int tt = l; tt < D1; tt += 64)
            W2i8[(size_t)o * D1 + tt] = (signed char)__float2int_rn(row[tt] * inv);
        return;
    }
    if (blk < 2720) {                                  // W3 row quant
        int p = (blk - 2656) * 4 + (t >> 6);
        int l = t & 63;
        const float* row = W3 + (size_t)p * D2;
        float m = 0.f;
        for (int tt = l; tt < D2; tt += 64) m = fmaxf(m, fabsf(row[tt]));
        m = waveReduceMax(m);
        m = __shfl(m, 0, 64);
        m = fmaxf(m, 1e-20f);
        if (l == 0) s3q[p] = m / 127.f;
        float inv = 127.f / m;
        for (int tt = l; tt < D2; tt += 64)
            W3i8[(size_t)p * D2 + tt] = (signed char)__float2int_rn(row[tt] * inv);
        return;
    }
    {                                                  // rn1 (W1 row norms)
        int gw = (blk - 2720) * 4 + (t >> 6);
        int lane = t & 63;
        const float* row = W1 + (size_t)gw * D;
        float s = 0.f;
        for (int tt = lane; tt < D; tt += 64) { float v = row[tt]; s += v * v; }
        s = waveReduceSum(s);
        if (lane == 0) rn1[gw] = sqrtf(s);
    }
}

// ---- compensated bf16 MFMA mainloop, 64x64 tile, K range [k0, k0+KL) -------
template <int KD, int KL>
__device__ __forceinline__ void mfma3_64(
    const unsigned short* __restrict__ Ahi, const unsigned short* __restrict__ Alo,
    const unsigned short* __restrict__ Bhi, const unsigned short* __restrict__ Blo,
    int m0, int n0, int k0, unsigned short* sm, f32x4 acc[2][2]) {
    int tid = threadIdx.x;
    int l = tid & 63, w = tid >> 6;
    int rsub = l >> 2;
    int quad = l >> 4, l16 = l & 15;
    int wm = (w >> 1) * 32, wn = (w & 1) * 32;
    unsigned short* sAh = sm;
    unsigned short* sAl = sm + 2048;
    unsigned short* sBh = sm + 4096;
    unsigned short* sBl = sm + 6144;
    ptrdiff_t dA = Alo - Ahi, dB = Blo - Bhi;
    int rloc = w * 16 + rsub;
    int c = swz_src(rloc, l);
    const unsigned short* pa = Ahi + (size_t)(m0 + rloc) * KD + k0 + c * 8;
    const unsigned short* pb = Bhi + (size_t)(n0 + rloc) * KD + k0 + c * 8;
    int aoff[2], boff[2];
    #pragma unroll
    for (int mt = 0; mt < 2; mt++) aoff[mt] = swz_frag(wm + mt * 16 + l16, quad);
    #pragma unroll
    for (int nt = 0; nt < 2; nt++) boff[nt] = swz_frag(wn + nt * 16 + l16, quad);
    for (int kk = 0; kk < KL; kk += 32) {
        gld16(pa + kk,      sAh + w * 512);
        gld16(pa + dA + kk, sAl + w * 512);
        gld16(pb + kk,      sBh + w * 512);
        gld16(pb + dB + kk, sBl + w * 512);
        __syncthreads();
        short8 ah[2], al[2], bh[2], bl[2];
        #pragma unroll
        for (int mt = 0; mt < 2; mt++) {
            ah[mt] = *(const short8*)(sAh + aoff[mt]);
            al[mt] = *(const short8*)(sAl + aoff[mt]);
        }
        #pragma unroll
        for (int nt = 0; nt < 2; nt++) {
            bh[nt] = *(const short8*)(sBh + boff[nt]);
            bl[nt] = *(const short8*)(sBl + boff[nt]);
        }
        #pragma unroll
        for (int mt = 0; mt < 2; mt++)
            #pragma unroll
            for (int nt = 0; nt < 2; nt++) {
                acc[mt][nt] = __builtin_amdgcn_mfma_f32_16x16x32_bf16(ah[mt], bh[nt], acc[mt][nt], 0, 0, 0);
                acc[mt][nt] = __builtin_amdgcn_mfma_f32_16x16x32_bf16(ah[mt], bl[nt], acc[mt][nt], 0, 0, 0);
                acc[mt][nt] = __builtin_amdgcn_mfma_f32_16x16x32_bf16(al[mt], bh[nt], acc[mt][nt], 0, 0, 0);
            }
        __syncthreads();
    }
}

// ---- layer 1: z1 -> dist1 (stride D1), m1q bytes, h1 hi/lo -----------------
__global__ __launch_bounds__(256) void k_l1(
    const unsigned short* __restrict__ xhi,  const unsigned short* __restrict__ xlo,
    const unsigned short* __restrict__ W1hi, const unsigned short* __restrict__ W1lo,
    const float* __restrict__ b1, const float* __restrict__ rn1,
    float* __restrict__ dists, unsigned char* __restrict__ m1q,
    unsigned short* __restrict__ h1hi, unsigned short* __restrict__ h1lo) {
    __shared__ __align__(16) unsigned short sm[8192];
    int m0 = blockIdx.x * 64, n0 = blockIdx.y * 64;
    f32x4 acc[2][2] = {};
    mfma3_64<D, D>(xhi, xlo, W1hi, W1lo, m0, n0, 0, sm, acc);
    int l = threadIdx.x & 63, w = threadIdx.x >> 6;
    int quad = l >> 4, l16 = l & 15;
    int wm = (w >> 1) * 32, wn = (w & 1) * 32;
    #pragma unroll
    for (int mt = 0; mt < 2; mt++)
        #pragma unroll
        for (int nt = 0; nt < 2; nt++) {
            int n = n0 + wn + nt * 16 + l16;
            float bv = b1[n], rv = rn1[n];
            #pragma unroll
            for (int r = 0; r < 4; r++) {
                int m = m0 + wm + mt * 16 + quad * 4 + r;
                float z = acc[mt][nt][r] + bv;
                size_t idx = (size_t)m * D1 + n;
                dists[idx] = fabsf(z) / rv;
                m1q[idx] = (z > 0.f) ? 0xFFu : 0u;
                float h = z > 0.f ? z : 0.f;
                unsigned short hh = f2bf(h);
                h1hi[idx] = hh;
                h1lo[idx] = f2bf(h - bf2f(hh));
            }
        }
}

// ---- merged dispatch 1: l2a (blocks 0..127) || gemm1 (128..2175) -----------
__global__ __launch_bounds__(256) void k_big1(
    const unsigned short* __restrict__ h1hi, const unsigned short* __restrict__ h1lo,
    const unsigned short* __restrict__ W2hi, const unsigned short* __restrict__ W2lo,
    float* __restrict__ z2,
    const signed char* __restrict__ W1Ti8,   // [256][1024]  A rows (d)
    const signed char* __restrict__ W2i8,    // [512][1024]  B rows (o)
    const unsigned char* __restrict__ m1q,   // [B][1024]
    const float* __restrict__ saq,           // [256]
    const float* __restrict__ sbq,           // [512]
    signed char* __restrict__ qV2,           // [256][256][512] (d-major)
    float* __restrict__ norm2) {             // [B][512]
    __shared__ __align__(16) unsigned char smem[32768];
    int bid = blockIdx.x;

    if (bid < 128) {
        // ---- l2a: split-K partial z2 (atomic; bias folded downstream) ----
        unsigned short* sm = (unsigned short*)smem;
        int m0 = (bid & 3) * 64, n0 = ((bid >> 2) & 7) * 64, k0 = (bid >> 5) * 256;
        f32x4 acc[2][2] = {};
        mfma3_64<D1, 256>(h1hi, h1lo, W2hi, W2lo, m0, n0, k0, sm, acc);
        int l = threadIdx.x & 63, w = threadIdx.x >> 6;
        int quad = l >> 4, l16 = l & 15;
        int wm = (w >> 1) * 32, wn = (w & 1) * 32;
        #pragma unroll
        for (int mt = 0; mt < 2; mt++)
            #pragma unroll
            for (int nt = 0; nt < 2; nt++) {
                int n = n0 + wn + nt * 16 + l16;
                #pragma unroll
                for (int r = 0; r < 4; r++) {
                    int m = m0 + wm + mt * 16 + quad * 4 + r;
                    atomicAdd(&z2[(size_t)m * D2 + n], acc[mt][nt][r]);
                }
            }
        return;
    }

    // ---- gemm1 (i8, BK=128, M=d/N=o, mask on A; R11 direct-store epilogue) --
    int j = bid - 128;
    signed char* As = (signed char*)smem;
    signed char* Bs = (signed char*)smem + 16384;
    int m0 = (j & 1) * 128;           // d
    int o0 = ((j >> 1) & 3) * 128;    // o
    int b = j >> 3;                   // batch
    int tid = threadIdx.x;
    int l = tid & 63, w = tid >> 6;
    int quad = l >> 4, l16 = l & 15;
    int wm = (w >> 1) * 64, wn = (w & 1) * 64;
    const unsigned char* mrow = m1q + (size_t)b * D1;

    const signed char* pa[4];
    const signed char* pb[4];
    int lrow = l >> 3, ls = l & 7;
    #pragma unroll
    for (int r = 0; r < 4; r++) {
        int row = r * 32 + w * 8 + lrow;
        int c = (ls + (row & 7)) & 7;
        pa[r] = W1Ti8 + (size_t)(m0 + row) * D1 + c * 16;
        pb[r] = W2i8 + (size_t)(o0 + row) * D1 + c * 16;
    }
    int aoff[4][2], boff[4][2];
    #pragma unroll
    for (int mt = 0; mt < 4; mt++) {
        int tr = wm + mt * 16 + l16;
        #pragma unroll
        for (int ks = 0; ks < 2; ks++)
            aoff[mt][ks] = tr * 128 + (((ks * 4 + quad) - (tr & 7)) & 7) * 16;
    }
    #pragma unroll
    for (int nt = 0; nt < 4; nt++) {
        int tr = wn + nt * 16 + l16;
        #pragma unroll
        for (int ks = 0; ks < 2; ks++)
            boff[nt][ks] = tr * 128 + (((ks * 4 + quad) - (tr & 7)) & 7) * 16;
    }

    i32x4 acc[4][4];
    #pragma unroll
    for (int i = 0; i < 4; i++)
        #pragma unroll
        for (int jj = 0; jj < 4; jj++) acc[i][jj] = (i32x4)0;

    for (int kk = 0; kk < D1; kk += 128) {
        #pragma unroll
        for (int r = 0; r < 4; r++) {
            gld16(pa[r] + kk, As + r * 4096 + w * 1024);
            gld16(pb[r] + kk, Bs + r * 4096 + w * 1024);
        }
        i32x4 mv0 = *(const i32x4*)(mrow + kk + quad * 16);
        i32x4 mv1 = *(const i32x4*)(mrow + kk + 64 + quad * 16);
        __syncthreads();
        #pragma unroll
        for (int ks = 0; ks < 2; ks++) {
            i32x4 mv = ks ? mv1 : mv0;
            i32x4 a[4], bq[4];
            #pragma unroll
            for (int mt = 0; mt < 4; mt++)
                a[mt] = (*(const i32x4*)(As + aoff[mt][ks])) & mv;
            #pragma unroll
            for (int nt = 0; nt < 4; nt++)
                bq[nt] = *(const i32x4*)(Bs + boff[nt][ks]);
            #pragma unroll
            for (int mt = 0; mt < 4; mt++)
                #pragma unroll
                for (int nt = 0; nt < 4; nt++)
                    acc[mt][nt] = __builtin_amdgcn_mfma_i32_16x16x64_i8(
                        a[mt], bq[nt], acc[mt][nt], 0, 0, 0);
        }
        __syncthreads();
    }

    float sad[4][4];
    #pragma unroll
    for (int mt = 0; mt < 4; mt++)
        #pragma unroll
        for (int r = 0; r < 4; r++)
            sad[mt][r] = saq[m0 + wm + mt * 16 + quad * 4 + r];
    float sbv[4], sbdq[4];
    #pragma unroll
    for (int nt = 0; nt < 4; nt++) {
        sbv[nt] = sbq[o0 + wn + nt * 16 + l16];
        sbdq[nt] = sbv[nt] * (1.0f / CQ);
    }

    // norm2[o] += sum_d V2^2
    #pragma unroll
    for (int nt = 0; nt < 4; nt++) {
        float s = 0.f;
        #pragma unroll
        for (int mt = 0; mt < 4; mt++)
            #pragma unroll
            for (int r = 0; r < 4; r++) {
                float v = (float)acc[mt][nt][r] * sad[mt][r] * sbv[nt];
                s += v * v;
            }
        s += __shfl_down(s, 32, 64);
        s += __shfl_down(s, 16, 64);
        if (l < 16)
            atomicAdd(&norm2[(size_t)b * D2 + o0 + wn + nt * 16 + l], s);
    }

    // qV2[d][o] int8 direct byte stores (R11-proven; 0 conflicts)
    signed char* qb = qV2 + (size_t)b * (D * D2);
    #pragma unroll
    for (int mt = 0; mt < 4; mt++) {
        int dbase = m0 + wm + mt * 16 + quad * 4;
        #pragma unroll
        for (int r = 0; r < 4; r++)
            #pragma unroll
            for (int nt = 0; nt < 4; nt++) {
                int o = o0 + wn + nt * 16 + l16;
                int qi = __float2int_rn((float)acc[mt][nt][r] * sbdq[nt]);
                qi = max(-127, min(127, qi));
                qb[(size_t)(dbase + r) * D2 + o] = (signed char)qi;
            }
    }
}

// ---- merged dispatch 2: l3a z2-direct (0..31) || gemm2 (32..1055) ----------
__global__ __launch_bounds__(256) void k_big2(
    const float* __restrict__ z2,            // [B][512] (bias NOT applied)
    const float* __restrict__ b2,            // [512]
    const unsigned short* __restrict__ W3hi, const unsigned short* __restrict__ W3lo,
    float* __restrict__ z3,
    const signed char* __restrict__ W3i8,    // [256][512]
    const signed char* __restrict__ qV2,     // [256][256][512]
    const float* __restrict__ saq,           // [256]
    const float* __restrict__ s3q,           // [256]
    float* __restrict__ norm3) {             // [B][256]
    __shared__ __align__(16) unsigned char smem[33280];  // 32K tiles + 512B mask
    int bid = blockIdx.x;
    int tid = threadIdx.x;

    if (bid < 32) {
        // ---- l3a: split-K partial z3; A = relu(z2+b2) hi/lo computed inline
        unsigned short* sAh = (unsigned short*)smem;
        unsigned short* sAl = sAh + 2048;
        unsigned short* sBh = sAh + 4096;
        unsigned short* sBl = sAh + 6144;
        int m0 = (bid & 3) * 64, n0 = ((bid >> 2) & 3) * 64, k0 = (bid >> 4) * 256;
        int l = tid & 63, w = tid >> 6;
        int rsub = l >> 2;
        int quad = l >> 4, l16 = l & 15;
        int wm = (w >> 1) * 32, wn = (w & 1) * 32;
        int rloc = w * 16 + rsub;
        int c = swz_src(rloc, l);
        const float* pz  = z2 + (size_t)(m0 + rloc) * D2 + k0 + c * 8;
        const float* pbi = b2 + k0 + c * 8;
        const unsigned short* pb = W3hi + (size_t)(n0 + rloc) * D2 + k0 + c * 8;
        ptrdiff_t dB = W3lo - W3hi;
        int aoff[2], boff[2];
        #pragma unroll
        for (int mt = 0; mt < 2; mt++) aoff[mt] = swz_frag(wm + mt * 16 + l16, quad);
        #pragma unroll
        for (int nt = 0; nt < 2; nt++) boff[nt] = swz_frag(wn + nt * 16 + l16, quad);
        int wrA = w * 512 + l * 8;
        f32x4 acc[2][2] = {};
        for (int kk = 0; kk < 256; kk += 32) {
            gld16(pb + kk,      sBh + w * 512);
            gld16(pb + dB + kk, sBl + w * 512);
            float4 za = *(const float4*)(pz + kk);
            float4 zb = *(const float4*)(pz + kk + 4);
            float4 ba = *(const float4*)(pbi + kk);
            float4 bb = *(const float4*)(pbi + kk + 4);
            float hv[8] = { za.x + ba.x, za.y + ba.y, za.z + ba.z, za.w + ba.w,
                            zb.x + bb.x, zb.y + bb.y, zb.z + bb.z, zb.w + bb.w };
            short8 h8, l8;
            #pragma unroll
            for (int q2 = 0; q2 < 8; q2++) {
                float h = hv[q2] > 0.f ? hv[q2] : 0.f;
                unsigned short hh = f2bf(h);
                h8[q2] = (short)hh;
                l8[q2] = (short)f2bf(h - bf2f(hh));
            }
            *(short8*)(sAh + wrA) = h8;
            *(short8*)(sAl + wrA) = l8;
            __syncthreads();
            short8 ah[2], al[2], bh[2], bl[2];
            #pragma unroll
            for (int mt = 0; mt < 2; mt++) {
                ah[mt] = *(const short8*)(sAh + aoff[mt]);
                al[mt] = *(const short8*)(sAl + aoff[mt]);
            }
            #pragma unroll
            for (int nt = 0; nt < 2; nt++) {
                bh[nt] = *(const short8*)(sBh + boff[nt]);
                bl[nt] = *(const short8*)(sBl + boff[nt]);
            }
            #pragma unroll
            for (int mt = 0; mt < 2; mt++)
                #pragma unroll
                for (int nt = 0; nt < 2; nt++) {
                    acc[mt][nt] = __builtin_amdgcn_mfma_f32_16x16x32_bf16(ah[mt], bh[nt], acc[mt][nt], 0, 0, 0);
                    acc[mt][nt] = __builtin_amdgcn_mfma_f32_16x16x32_bf16(ah[mt], bl[nt], acc[mt][nt], 0, 0, 0);
                    acc[mt][nt] = __builtin_amdgcn_mfma_f32_16x16x32_bf16(al[mt], bh[nt], acc[mt][nt], 0, 0, 0);
                }
            __syncthreads();
        }
        #pragma unroll
        for (int mt = 0; mt < 2; mt++)
            #pragma unroll
            for (int nt = 0; nt < 2; nt++) {
                int n = n0 + wn + nt * 16 + l16;
                #pragma unroll
                for (int r = 0; r < 4; r++) {
                    int m = m0 + wm + mt * 16 + quad * 4 + r;
                    atomicAdd(&z3[(size_t)m * D3 + n], acc[mt][nt][r]);
                }
            }
        return;
    }

    // ---- gemm2 (i8, BK=128): norm3; m2 mask from z2+b2 in LDS ----
    int j = bid - 32;
    signed char* As = (signed char*)smem;
    signed char* Bs = (signed char*)smem + 16384;
    unsigned char* mbuf = (unsigned char*)smem + 32768;  // 512 B
    int m0 = (j & 1) * 128;           // p
    int n0 = ((j >> 1) & 1) * 128;    // d
    int bc = j >> 2;                  // batch
    int l = tid & 63, w = tid >> 6;
    int quad = l >> 4, l16 = l & 15;
    int wm = (w >> 1) * 64, wn = (w & 1) * 64;
    const signed char* Bsrc = qV2 + (size_t)bc * (D * D2);

    {   // fill m2 mask row for this batch
        #pragma unroll
        for (int rr = 0; rr < 2; rr++) {
            int o = tid * 2 + rr;
            float z = z2[(size_t)bc * D2 + o] + b2[o];
            mbuf[o] = (z > 0.f) ? 0xFFu : 0u;
        }
    }
    __syncthreads();

    const signed char* pa[4];
    const signed char* pb[4];
    int lrow = l >> 3, ls = l & 7;
    #pragma unroll
    for (int r = 0; r < 4; r++) {
        int row = r * 32 + w * 8 + lrow;
        int c = (ls + (row & 7)) & 7;
        pa[r] = W3i8 + (size_t)(m0 + row) * D2 + c * 16;
        pb[r] = Bsrc + (size_t)(n0 + row) * D2 + c * 16;
    }
    int aoff[4][2], boff[4][2];
    #pragma unroll
    for (int mt = 0; mt < 4; mt++) {
        int tr = wm + mt * 16 + l16;
        #pragma unroll
        for (int ks = 0; ks < 2; ks++)
            aoff[mt][ks] = tr * 128 + (((ks * 4 + quad) - (tr & 7)) & 7) * 16;
    }
    #pragma unroll
    for (int nt = 0; nt < 4; nt++) {
        int tr = wn + nt * 16 + l16;
        #pragma unroll
        for (int ks = 0; ks < 2; ks++)
            boff[nt][ks] = tr * 128 + (((ks * 4 + quad) - (tr & 7)) & 7) * 16;
    }

    i32x4 acc[4][4];
    #pragma unroll
    for (int i = 0; i < 4; i++)
        #pragma unroll
        for (int jj = 0; jj < 4; jj++) acc[i][jj] = (i32x4)0;

    for (int kk = 0; kk < D2; kk += 128) {
        #pragma unroll
        for (int r = 0; r < 4; r++) {
            gld16(pa[r] + kk, As + r * 4096 + w * 1024);
            gld16(pb[r] + kk, Bs + r * 4096 + w * 1024);
        }
        __syncthreads();
        i32x4 mv0 = *(const i32x4*)(mbuf + kk + quad * 16);
        i32x4 mv1 = *(const i32x4*)(mbuf + kk + 64 + quad * 16);
        #pragma unroll
        for (int ks = 0; ks < 2; ks++) {
            i32x4 mv = ks ? mv1 : mv0;
            i32x4 a[4], bq[4];
            #pragma unroll
            for (int mt = 0; mt < 4; mt++)
                a[mt] = *(const i32x4*)(As + aoff[mt][ks]);
            #pragma unroll
            for (int nt = 0; nt < 4; nt++)
                bq[nt] = (*(const i32x4*)(Bs + boff[nt][ks])) & mv;
            #pragma unroll
            for (int mt = 0; mt < 4; mt++)
                #pragma unroll
                for (int nt = 0; nt < 4; nt++)
                    acc[mt][nt] = __builtin_amdgcn_mfma_i32_16x16x64_i8(
                        a[mt], bq[nt], acc[mt][nt], 0, 0, 0);
        }
        __syncthreads();
    }

    float saCQ[4];
    #pragma unroll
    for (int nt = 0; nt < 4; nt++)
        saCQ[nt] = saq[n0 + wn + nt * 16 + l16] * CQ;

    #pragma unroll
    for (int mt = 0; mt < 4; mt++)
        #pragma unroll
        for (int r = 0; r < 4; r++) {
            float s = 0.f;
            #pragma unroll
            for (int nt = 0; nt < 4; nt++) {
                float v = (float)acc[mt][nt][r] * saCQ[nt];
                s += v * v;
            }
            s += __shfl_down(s, 8, 64);
            s += __shfl_down(s, 4, 64);
            s += __shfl_down(s, 2, 64);
            s += __shfl_down(s, 1, 64);
            if (l16 == 0) {
                int p = m0 + wm + mt * 16 + quad * 4 + r;
                float s3 = s3q[p];
                atomicAdd(&norm3[(size_t)bc * D3 + p], s * s3 * s3);
            }
        }
}

// ---- wave-per-batch k-smallest sum (barrier-free butterfly) ----------------
// 64 blocks x 4 waves; each wave owns one batch: 28 dists/lane, 10 rounds.
__global__ __launch_bounds__(256) void k_topk(
    const float* __restrict__ dists,    // [B][D1] dist1 only
    const float* __restrict__ z2, const float* __restrict__ b2,
    const float* __restrict__ norm2,
    const float* __restrict__ z3, const float* __restrict__ b3,
    const float* __restrict__ norm3,
    const int* __restrict__ kp, float* __restrict__ outp) {
    int t = threadIdx.x;
    int wv = t >> 6, lane = t & 63;
    int b = blockIdx.x * 4 + wv;
    float lv[28];
    #pragma unroll
    for (int j = 0; j < 16; j++)
        lv[j] = dists[(size_t)b * D1 + lane + 64 * j];
    #pragma unroll
    for (int j = 16; j < 24; j++) {
        int o = lane + 64 * (j - 16);
        float zz = z2[(size_t)b * D2 + o] + b2[o];
        lv[j] = fabsf(zz) / sqrtf(norm2[(size_t)b * D2 + o]);
    }
    #pragma unroll
    for (int j = 24; j < 28; j++) {
        int p = lane + 64 * (j - 24);
        float zz = z3[(size_t)b * D3 + p] + b3[p];
        lv[j] = fabsf(zz) / sqrtf(norm3[(size_t)b * D3 + p]);
    }
    int k = *kp;
    if (k > NDIST) k = NDIST;
    float sum = 0.f;
    for (int it = 0; it < k; it++) {
        float mv = lv[0]; int mj = 0;
        #pragma unroll
        for (int j = 1; j < 28; j++)
            if (lv[j] < mv) { mv = lv[j]; mj = j; }
        unsigned long long key =
            ((unsigned long long)__float_as_uint(mv) << 32) | (unsigned)(lane * 32 + mj);
        #pragma unroll
        for (int off = 1; off < 64; off <<= 1) {
            unsigned long long o = __shfl_xor(key, off, 64);
            if (o < key) key = o;
        }
        sum += __uint_as_float((unsigned)(key >> 32));
        int wl = (int)((key >> 5) & 63u), wj = (int)(key & 31u);
        if (lane == wl) lv[wj] = FLT_MAX;
    }
    if (lane == 0) atomicAdd(outp, sum);
}

extern "C" void kernel_launch(void* const* d_in, const int* in_sizes, int n_in,
                              void* d_out, int out_size, void* d_ws, size_t ws_size,
                              hipStream_t stream) {
    const float* x  = (const float*)d_in[0];
    const float* W1 = (const float*)d_in[1];
    const float* b1 = (const float*)d_in[2];
    const float* W2 = (const float*)d_in[3];
    const float* b2 = (const float*)d_in[4];
    const float* W3 = (const float*)d_in[5];
    const float* b3 = (const float*)d_in[6];
    const int*   kp = (const int*)d_in[7];
    float* outp = (float*)d_out;

    float* fp = (float*)d_ws;
    float* rn1     = fp;                          fp += D1;
    float* dists   = fp;                          fp += (size_t)B * D1;
    float* saq     = fp;                          fp += D;
    float* sbq     = fp;                          fp += D2;
    float* s3q     = fp;                          fp += D3;
    // zero region: z2 || z3 || norm2 || norm3 (contiguous, 393216 floats)
    float* z2      = fp;                          fp += (size_t)B * D2;
    float* z3      = fp;                          fp += (size_t)B * D3;
    float* norm2   = fp;                          fp += (size_t)B * D2;
    float* norm3   = fp;                          fp += (size_t)B * D3;
    unsigned short* up = (unsigned short*)fp;
    unsigned short* W2hi  = up;  up += (size_t)D2 * D1;
    unsigned short* W2lo  = up;  up += (size_t)D2 * D1;
    unsigned short* W3hi  = up;  up += (size_t)D3 * D2;
    unsigned short* W3lo  = up;  up += (size_t)D3 * D2;
    unsigned short* xhi   = up;  up += (size_t)B * D;
    unsigned short* xlo   = up;  up += (size_t)B * D;
    unsigned short* W1hi  = up;  up += (size_t)D1 * D;
    unsigned short* W1lo  = up;  up += (size_t)D1 * D;
    unsigned short* h1hi  = up;  up += (size_t)B * D1;
    unsigned short* h1lo  = up;  up += (size_t)B * D1;
    signed char*    cp = (signed char*)up;
    signed char*    W1Ti8 = cp;  cp += (size_t)D * D1;
    signed char*    W2i8  = cp;  cp += (size_t)D2 * D1;
    signed char*    W3i8  = cp;  cp += (size_t)D3 * D2;
    unsigned char*  m1q   = (unsigned char*)cp;  cp += (size_t)B * D1;
    signed char*    qV2   = cp;   // full 256-batch (33.5 MB; ws proven since R10)

    k_prep<<<2976, 256, 0, stream>>>(x, W1, W2, W3, z2, outp,
                                     xhi, xlo, W1hi, W1lo, W2hi, W2lo, W3hi, W3lo,
                                     W1Ti8, saq, W2i8, sbq, W3i8, s3q, rn1);

    k_l1<<<dim3(B / 64, D1 / 64), 256, 0, stream>>>(xhi, xlo, W1hi, W1lo, b1, rn1,
                                                    dists, m1q, h1hi, h1lo);

    // l2a (128) || gemm1 (2048)
    k_big1<<<2176, 256, 0, stream>>>(h1hi, h1lo, W2hi, W2lo, z2,
                                     W1Ti8, W2i8, m1q, saq, sbq, qV2, norm2);

    // l3a z2-direct (32) || gemm2 mask-from-LDS (1024)
    k_big2<<<1056, 256, 0, stream>>>(z2, b2, W3hi, W3lo, z3,
                                     W3i8, qV2, saq, s3q, norm3);

    k_topk<<<B / 4, 256, 0, stream>>>(dists, z2, b2, norm2, z3, b3, norm3, kp, outp);
}

// Round 15
// 177.875 us; speedup vs baseline: 1.0971x; 1.0186x over previous
//
#include <hip/hip_runtime.h>
#include <math.h>
#include <float.h>

#define B   256
#define D   256
#define D1  1024
#define D2  512
#define D3  256
#define NDIST (D1 + D2 + D3)   // 1792
#define CQ  2.0f               // qV2 static scale multiplier (step = sa[d]*CQ)

typedef __attribute__((ext_vector_type(8))) short short8;
typedef __attribute__((ext_vector_type(4))) float f32x4;
typedef __attribute__((ext_vector_type(4))) int   i32x4;

__device__ __forceinline__ float waveReduceSum(float v) {
    #pragma unroll
    for (int off = 32; off > 0; off >>= 1)
        v += __shfl_down(v, off, 64);
    return v;
}
__device__ __forceinline__ float waveReduceMax(float v) {
    #pragma unroll
    for (int off = 32; off > 0; off >>= 1)
        v = fmaxf(v, __shfl_down(v, off, 64));
    return v;
}
__device__ __forceinline__ unsigned short f2bf(float f) {
    unsigned int u = __float_as_uint(f);
    u = (u + 0x7FFFu + ((u >> 16) & 1u)) >> 16;   // RNE
    return (unsigned short)u;
}
__device__ __forceinline__ float bf2f(unsigned short h) {
    return __uint_as_float(((unsigned int)h) << 16);
}
__device__ __forceinline__ void gld16(const void* g, void* l) {
    __builtin_amdgcn_global_load_lds(
        (const __attribute__((address_space(1))) unsigned int*)g,
        (__attribute__((address_space(3))) unsigned int*)l, 16, 0, 0);
}
__device__ __forceinline__ int swz_src(int row, int lane) {
    return ((lane & 3) + ((row >> 1) & 3)) & 3;
}
__device__ __forceinline__ int swz_frag(int row, int quad) {
    return row * 32 + (((quad - ((row >> 1) & 3)) & 3) * 8);
}

__device__ __forceinline__ void split_job(const float* src, unsigned short* hi,
                                          unsigned short* lo, int off) {
    float4 v = *(const float4*)(src + off);
    ushort4 h, l;
    h.x = f2bf(v.x); l.x = f2bf(v.x - bf2f(h.x));
    h.y = f2bf(v.y); l.y = f2bf(v.y - bf2f(h.y));
    h.z = f2bf(v.z); l.z = f2bf(v.z - bf2f(h.z));
    h.w = f2bf(v.w); l.w = f2bf(v.w - bf2f(h.w));
    *(ushort4*)(hi + off) = h;
    *(ushort4*)(lo + off) = l;
}

// ---- prep-A: only what l1 needs — x/W1 hi-lo splits + rn1 (576 blocks) -----
__global__ __launch_bounds__(256) void k_prepA(
    const float* __restrict__ x, const float* __restrict__ W1,
    unsigned short* __restrict__ xhi,  unsigned short* __restrict__ xlo,
    unsigned short* __restrict__ W1hi, unsigned short* __restrict__ W1lo,
    float* __restrict__ rn1) {
    int blk = blockIdx.x;
    int t = threadIdx.x;
    if (blk < 64) {                                    // x split (65536)
        split_job(x, xhi, xlo, blk * 1024 + t * 4);
        return;
    }
    if (blk < 320) {                                   // W1 split (262144)
        split_job(W1, W1hi, W1lo, (blk - 64) * 1024 + t * 4);
        return;
    }
    {                                                  // rn1 (1024 rows)
        int gw = (blk - 320) * 4 + (t >> 6);
        int lane = t & 63;
        const float* row = W1 + (size_t)gw * D;
        float s = 0.f;
        for (int tt = lane; tt < D; tt += 64) { float v = row[tt]; s += v * v; }
        s = waveReduceSum(s);
        if (lane == 0) rn1[gw] = sqrtf(s);
    }
}

// ---- compensated bf16 MFMA mainloop, 64x64 tile, K range [k0, k0+KL) -------
template <int KD, int KL>
__device__ __forceinline__ void mfma3_64(
    const unsigned short* __restrict__ Ahi, const unsigned short* __restrict__ Alo,
    const unsigned short* __restrict__ Bhi, const unsigned short* __restrict__ Blo,
    int m0, int n0, int k0, unsigned short* sm, f32x4 acc[2][2]) {
    int tid = threadIdx.x;
    int l = tid & 63, w = tid >> 6;
    int rsub = l >> 2;
    int quad = l >> 4, l16 = l & 15;
    int wm = (w >> 1) * 32, wn = (w & 1) * 32;
    unsigned short* sAh = sm;
    unsigned short* sAl = sm + 2048;
    unsigned short* sBh = sm + 4096;
    unsigned short* sBl = sm + 6144;
    ptrdiff_t dA = Alo - Ahi, dB = Blo - Bhi;
    int rloc = w * 16 + rsub;
    int c = swz_src(rloc, l);
    const unsigned short* pa = Ahi + (size_t)(m0 + rloc) * KD + k0 + c * 8;
    const unsigned short* pb = Bhi + (size_t)(n0 + rloc) * KD + k0 + c * 8;
    int aoff[2], boff[2];
    #pragma unroll
    for (int mt = 0; mt < 2; mt++) aoff[mt] = swz_frag(wm + mt * 16 + l16, quad);
    #pragma unroll
    for (int nt = 0; nt < 2; nt++) boff[nt] = swz_frag(wn + nt * 16 + l16, quad);
    for (int kk = 0; kk < KL; kk += 32) {
        gld16(pa + kk,      sAh + w * 512);
        gld16(pa + dA + kk, sAl + w * 512);
        gld16(pb + kk,      sBh + w * 512);
        gld16(pb + dB + kk, sBl + w * 512);
        __syncthreads();
        short8 ah[2], al[2], bh[2], bl[2];
        #pragma unroll
        for (int mt = 0; mt < 2; mt++) {
            ah[mt] = *(const short8*)(sAh + aoff[mt]);
            al[mt] = *(const short8*)(sAl + aoff[mt]);
        }
        #pragma unroll
        for (int nt = 0; nt < 2; nt++) {
            bh[nt] = *(const short8*)(sBh + boff[nt]);
            bl[nt] = *(const short8*)(sBl + boff[nt]);
        }
        #pragma unroll
        for (int mt = 0; mt < 2; mt++)
            #pragma unroll
            for (int nt = 0; nt < 2; nt++) {
                acc[mt][nt] = __builtin_amdgcn_mfma_f32_16x16x32_bf16(ah[mt], bh[nt], acc[mt][nt], 0, 0, 0);
                acc[mt][nt] = __builtin_amdgcn_mfma_f32_16x16x32_bf16(ah[mt], bl[nt], acc[mt][nt], 0, 0, 0);
                acc[mt][nt] = __builtin_amdgcn_mfma_f32_16x16x32_bf16(al[mt], bh[nt], acc[mt][nt], 0, 0, 0);
            }
        __syncthreads();
    }
}

// ---- dispatch 2: l1 gemm (0..63) + zeros + W2/W3 splits + i8 quants --------
// Everything except l1 depends only on kernel inputs; runs in l1's shadow.
__global__ __launch_bounds__(256) void k_l1p(
    const float* __restrict__ W1, const float* __restrict__ W2,
    const float* __restrict__ W3,
    const unsigned short* __restrict__ xhi,  const unsigned short* __restrict__ xlo,
    const unsigned short* __restrict__ W1hi, const unsigned short* __restrict__ W1lo,
    const float* __restrict__ b1, const float* __restrict__ rn1,
    float* __restrict__ dists, unsigned char* __restrict__ m1q,
    unsigned short* __restrict__ h1hi, unsigned short* __restrict__ h1lo,
    float* __restrict__ zeros, float* __restrict__ outp,
    unsigned short* __restrict__ W2hi, unsigned short* __restrict__ W2lo,
    unsigned short* __restrict__ W3hi, unsigned short* __restrict__ W3lo,
    signed char* __restrict__ W1Ti8, float* __restrict__ saq,
    signed char* __restrict__ W2i8,  float* __restrict__ sbq,
    signed char* __restrict__ W3i8,  float* __restrict__ s3q) {
    __shared__ __align__(16) unsigned short sm[8192];
    int blk = blockIdx.x;
    int t = threadIdx.x;

    if (blk < 64) {                                    // l1: z1 GEMM + epilogue
        int m0 = (blk & 3) * 64, n0 = (blk >> 2) * 64;
        f32x4 acc[2][2] = {};
        mfma3_64<D, D>(xhi, xlo, W1hi, W1lo, m0, n0, 0, sm, acc);
        int l = t & 63, w = t >> 6;
        int quad = l >> 4, l16 = l & 15;
        int wm = (w >> 1) * 32, wn = (w & 1) * 32;
        #pragma unroll
        for (int mt = 0; mt < 2; mt++)
            #pragma unroll
            for (int nt = 0; nt < 2; nt++) {
                int n = n0 + wn + nt * 16 + l16;
                float bv = b1[n], rv = rn1[n];
                #pragma unroll
                for (int r = 0; r < 4; r++) {
                    int m = m0 + wm + mt * 16 + quad * 4 + r;
                    float z = acc[mt][nt][r] + bv;
                    size_t idx = (size_t)m * D1 + n;
                    dists[idx] = fabsf(z) / rv;
                    m1q[idx] = (z > 0.f) ? 0xFFu : 0u;
                    float h = z > 0.f ? z : 0.f;
                    unsigned short hh = f2bf(h);
                    h1hi[idx] = hh;
                    h1lo[idx] = f2bf(h - bf2f(hh));
                }
            }
        return;
    }
    if (blk < 448) {                                   // zero region (float4)
        if (blk == 64 && t == 0) outp[0] = 0.f;
        int i4 = (blk - 64) * 1024 + t * 4;
        *(float4*)(zeros + i4) = make_float4(0.f, 0.f, 0.f, 0.f);
        return;
    }
    if (blk < 960) {                                   // W2 split (524288)
        split_job(W2, W2hi, W2lo, (blk - 448) * 1024 + t * 4);
        return;
    }
    if (blk < 1088) {                                  // W3 split (131072)
        split_job(W3, W3hi, W3lo, (blk - 960) * 1024 + t * 4);
        return;
    }
    if (blk < 1120) {                                  // W1 col quant -> W1Ti8
        int ty = t >> 5, tx = t & 31;
        int d = (blk - 1088) * 8 + ty;
        float m = 0.f;
        for (int i = tx; i < D1; i += 32) m = fmaxf(m, fabsf(W1[(size_t)i * D + d]));
        #pragma unroll
        for (int off = 16; off > 0; off >>= 1) m = fmaxf(m, __shfl_down(m, off, 32));
        m = __shfl(m, 0, 32);
        m = fmaxf(m, 1e-20f);
        if (tx == 0) saq[d] = m / 127.f;
        float inv = 127.f / m;
        for (int i = tx; i < D1; i += 32) {
            int q = __float2int_rn(W1[(size_t)i * D + d] * inv);
            W1Ti8[(size_t)d * D1 + i] = (signed char)q;
        }
        return;
    }
    if (blk < 1248) {                                  // W2 row quant
        int o = (blk - 1120) * 4 + (t >> 6);
        int l = t & 63;
        const float* row = W2 + (size_t)o * D1;
        float m = 0.f;
        for (int tt = l; tt < D1; tt += 64) m = fmaxf(m, fabsf(row[tt]));
        m = waveReduceMax(m);
        m = __shfl(m, 0, 64);
        m = fmaxf(m, 1e-20f);
        if (l == 0) sbq[o] = m / 127.f;
        float inv = 127.f / m;
        for (int tt = l; tt < D1; tt += 64)
            W2i8[(size_t)o * D1 + tt] = (signed char)__float2int_rn(row[tt] * inv);
        return;
    }
    {                                                  // W3 row quant (64 blks)
        int p = (blk - 1248) * 4 + (t >> 6);
        int l = t & 63;
        const float* row = W3 + (size_t)p * D2;
        float m = 0.f;
        for (int tt = l; tt < D2; tt += 64) m = fmaxf(m, fabsf(row[tt]));
        m = waveReduceMax(m);
        m = __shfl(m, 0, 64);
        m = fmaxf(m, 1e-20f);
        if (l == 0) s3q[p] = m / 127.f;
        float inv = 127.f / m;
        for (int tt = l; tt < D2; tt += 64)
            W3i8[(size_t)p * D2 + tt] = (signed char)__float2int_rn(row[tt] * inv);
    }
}

// ---- merged dispatch 3: l2a (blocks 0..127) || gemm1 (128..2175) -----------
__global__ __launch_bounds__(256) void k_big1(
    const unsigned short* __restrict__ h1hi, const unsigned short* __restrict__ h1lo,
    const unsigned short* __restrict__ W2hi, const unsigned short* __restrict__ W2lo,
    float* __restrict__ z2,
    const signed char* __restrict__ W1Ti8,   // [256][1024]  A rows (d)
    const signed char* __restrict__ W2i8,    // [512][1024]  B rows (o)
    const unsigned char* __restrict__ m1q,   // [B][1024]
    const float* __restrict__ saq,           // [256]
    const float* __restrict__ sbq,           // [512]
    signed char* __restrict__ qV2,           // [256][256][512] (d-major)
    float* __restrict__ norm2) {             // [B][512]
    __shared__ __align__(16) unsigned char smem[32768];
    int bid = blockIdx.x;

    if (bid < 128) {
        // ---- l2a: split-K partial z2 (atomic; bias folded downstream) ----
        unsigned short* sm = (unsigned short*)smem;
        int m0 = (bid & 3) * 64, n0 = ((bid >> 2) & 7) * 64, k0 = (bid >> 5) * 256;
        f32x4 acc[2][2] = {};
        mfma3_64<D1, 256>(h1hi, h1lo, W2hi, W2lo, m0, n0, k0, sm, acc);
        int l = threadIdx.x & 63, w = threadIdx.x >> 6;
        int quad = l >> 4, l16 = l & 15;
        int wm = (w >> 1) * 32, wn = (w & 1) * 32;
        #pragma unroll
        for (int mt = 0; mt < 2; mt++)
            #pragma unroll
            for (int nt = 0; nt < 2; nt++) {
                int n = n0 + wn + nt * 16 + l16;
                #pragma unroll
                for (int r = 0; r < 4; r++) {
                    int m = m0 + wm + mt * 16 + quad * 4 + r;
                    atomicAdd(&z2[(size_t)m * D2 + n], acc[mt][nt][r]);
                }
            }
        return;
    }

    // ---- gemm1 (i8, BK=128, M=d/N=o, mask on A; direct-store epilogue) ----
    int j = bid - 128;
    signed char* As = (signed char*)smem;
    signed char* Bs = (signed char*)smem + 16384;
    int m0 = (j & 1) * 128;           // d
    int o0 = ((j >> 1) & 3) * 128;    // o
    int b = j >> 3;                   // batch
    int tid = threadIdx.x;
    int l = tid & 63, w = tid >> 6;
    int quad = l >> 4, l16 = l & 15;
    int wm = (w >> 1) * 64, wn = (w & 1) * 64;
    const unsigned char* mrow = m1q + (size_t)b * D1;

    const signed char* pa[4];
    const signed char* pb[4];
    int lrow = l >> 3, ls = l & 7;
    #pragma unroll
    for (int r = 0; r < 4; r++) {
        int row = r * 32 + w * 8 + lrow;
        int c = (ls + (row & 7)) & 7;
        pa[r] = W1Ti8 + (size_t)(m0 + row) * D1 + c * 16;
        pb[r] = W2i8 + (size_t)(o0 + row) * D1 + c * 16;
    }
    int aoff[4][2], boff[4][2];
    #pragma unroll
    for (int mt = 0; mt < 4; mt++) {
        int tr = wm + mt * 16 + l16;
        #pragma unroll
        for (int ks = 0; ks < 2; ks++)
            aoff[mt][ks] = tr * 128 + (((ks * 4 + quad) - (tr & 7)) & 7) * 16;
    }
    #pragma unroll
    for (int nt = 0; nt < 4; nt++) {
        int tr = wn + nt * 16 + l16;
        #pragma unroll
        for (int ks = 0; ks < 2; ks++)
            boff[nt][ks] = tr * 128 + (((ks * 4 + quad) - (tr & 7)) & 7) * 16;
    }

    i32x4 acc[4][4];
    #pragma unroll
    for (int i = 0; i < 4; i++)
        #pragma unroll
        for (int jj = 0; jj < 4; jj++) acc[i][jj] = (i32x4)0;

    for (int kk = 0; kk < D1; kk += 128) {
        #pragma unroll
        for (int r = 0; r < 4; r++) {
            gld16(pa[r] + kk, As + r * 4096 + w * 1024);
            gld16(pb[r] + kk, Bs + r * 4096 + w * 1024);
        }
        i32x4 mv0 = *(const i32x4*)(mrow + kk + quad * 16);
        i32x4 mv1 = *(const i32x4*)(mrow + kk + 64 + quad * 16);
        __syncthreads();
        #pragma unroll
        for (int ks = 0; ks < 2; ks++) {
            i32x4 mv = ks ? mv1 : mv0;
            i32x4 a[4], bq[4];
            #pragma unroll
            for (int mt = 0; mt < 4; mt++)
                a[mt] = (*(const i32x4*)(As + aoff[mt][ks])) & mv;
            #pragma unroll
            for (int nt = 0; nt < 4; nt++)
                bq[nt] = *(const i32x4*)(Bs + boff[nt][ks]);
            #pragma unroll
            for (int mt = 0; mt < 4; mt++)
                #pragma unroll
                for (int nt = 0; nt < 4; nt++)
                    acc[mt][nt] = __builtin_amdgcn_mfma_i32_16x16x64_i8(
                        a[mt], bq[nt], acc[mt][nt], 0, 0, 0);
        }
        __syncthreads();
    }

    float sad[4][4];
    #pragma unroll
    for (int mt = 0; mt < 4; mt++)
        #pragma unroll
        for (int r = 0; r < 4; r++)
            sad[mt][r] = saq[m0 + wm + mt * 16 + quad * 4 + r];
    float sbv[4], sbdq[4];
    #pragma unroll
    for (int nt = 0; nt < 4; nt++) {
        sbv[nt] = sbq[o0 + wn + nt * 16 + l16];
        sbdq[nt] = sbv[nt] * (1.0f / CQ);
    }

    // norm2[o] += sum_d V2^2
    #pragma unroll
    for (int nt = 0; nt < 4; nt++) {
        float s = 0.f;
        #pragma unroll
        for (int mt = 0; mt < 4; mt++)
            #pragma unroll
            for (int r = 0; r < 4; r++) {
                float v = (float)acc[mt][nt][r] * sad[mt][r] * sbv[nt];
                s += v * v;
            }
        s += __shfl_down(s, 32, 64);
        s += __shfl_down(s, 16, 64);
        if (l < 16)
            atomicAdd(&norm2[(size_t)b * D2 + o0 + wn + nt * 16 + l], s);
    }

    // qV2[d][o] int8 direct byte stores (0 conflicts)
    signed char* qb = qV2 + (size_t)b * (D * D2);
    #pragma unroll
    for (int mt = 0; mt < 4; mt++) {
        int dbase = m0 + wm + mt * 16 + quad * 4;
        #pragma unroll
        for (int r = 0; r < 4; r++)
            #pragma unroll
            for (int nt = 0; nt < 4; nt++) {
                int o = o0 + wn + nt * 16 + l16;
                int qi = __float2int_rn((float)acc[mt][nt][r] * sbdq[nt]);
                qi = max(-127, min(127, qi));
                qb[(size_t)(dbase + r) * D2 + o] = (signed char)qi;
            }
    }
}

// ---- merged dispatch 4: l3a z2-direct (0..31) || gemm2 (32..1055) ----------
__global__ __launch_bounds__(256) void k_big2(
    const float* __restrict__ z2,            // [B][512] (bias NOT applied)
    const float* __restrict__ b2,            // [512]
    const unsigned short* __restrict__ W3hi, const unsigned short* __restrict__ W3lo,
    float* __restrict__ z3,
    const signed char* __restrict__ W3i8,    // [256][512]
    const signed char* __restrict__ qV2,     // [256][256][512]
    const float* __restrict__ saq,           // [256]
    const float* __restrict__ s3q,           // [256]
    float* __restrict__ norm3) {             // [B][256]
    __shared__ __align__(16) unsigned char smem[33280];  // 32K tiles + 512B mask
    int bid = blockIdx.x;
    int tid = threadIdx.x;

    if (bid < 32) {
        // ---- l3a: split-K partial z3; A = relu(z2+b2) hi/lo computed inline
        unsigned short* sAh = (unsigned short*)smem;
        unsigned short* sAl = sAh + 2048;
        unsigned short* sBh = sAh + 4096;
        unsigned short* sBl = sAh + 6144;
        int m0 = (bid & 3) * 64, n0 = ((bid >> 2) & 3) * 64, k0 = (bid >> 4) * 256;
        int l = tid & 63, w = tid >> 6;
        int rsub = l >> 2;
        int quad = l >> 4, l16 = l & 15;
        int wm = (w >> 1) * 32, wn = (w & 1) * 32;
        int rloc = w * 16 + rsub;
        int c = swz_src(rloc, l);
        const float* pz  = z2 + (size_t)(m0 + rloc) * D2 + k0 + c * 8;
        const float* pbi = b2 + k0 + c * 8;
        const unsigned short* pb = W3hi + (size_t)(n0 + rloc) * D2 + k0 + c * 8;
        ptrdiff_t dB = W3lo - W3hi;
        int aoff[2], boff[2];
        #pragma unroll
        for (int mt = 0; mt < 2; mt++) aoff[mt] = swz_frag(wm + mt * 16 + l16, quad);
        #pragma unroll
        for (int nt = 0; nt < 2; nt++) boff[nt] = swz_frag(wn + nt * 16 + l16, quad);
        int wrA = w * 512 + l * 8;
        f32x4 acc[2][2] = {};
        for (int kk = 0; kk < 256; kk += 32) {
            gld16(pb + kk,      sBh + w * 512);
            gld16(pb + dB + kk, sBl + w * 512);
            float4 za = *(const float4*)(pz + kk);
            float4 zb = *(const float4*)(pz + kk + 4);
            float4 ba = *(const float4*)(pbi + kk);
            float4 bb = *(const float4*)(pbi + kk + 4);
            float hv[8] = { za.x + ba.x, za.y + ba.y, za.z + ba.z, za.w + ba.w,
                            zb.x + bb.x, zb.y + bb.y, zb.z + bb.z, zb.w + bb.w };
            short8 h8, l8;
            #pragma unroll
            for (int q2 = 0; q2 < 8; q2++) {
                float h = hv[q2] > 0.f ? hv[q2] : 0.f;
                unsigned short hh = f2bf(h);
                h8[q2] = (short)hh;
                l8[q2] = (short)f2bf(h - bf2f(hh));
            }
            *(short8*)(sAh + wrA) = h8;
            *(short8*)(sAl + wrA) = l8;
            __syncthreads();
            short8 ah[2], al[2], bh[2], bl[2];
            #pragma unroll
            for (int mt = 0; mt < 2; mt++) {
                ah[mt] = *(const short8*)(sAh + aoff[mt]);
                al[mt] = *(const short8*)(sAl + aoff[mt]);
            }
            #pragma unroll
            for (int nt = 0; nt < 2; nt++) {
                bh[nt] = *(const short8*)(sBh + boff[nt]);
                bl[nt] = *(const short8*)(sBl + boff[nt]);
            }
            #pragma unroll
            for (int mt = 0; mt < 2; mt++)
                #pragma unroll
                for (int nt = 0; nt < 2; nt++) {
                    acc[mt][nt] = __builtin_amdgcn_mfma_f32_16x16x32_bf16(ah[mt], bh[nt], acc[mt][nt], 0, 0, 0);
                    acc[mt][nt] = __builtin_amdgcn_mfma_f32_16x16x32_bf16(ah[mt], bl[nt], acc[mt][nt], 0, 0, 0);
                    acc[mt][nt] = __builtin_amdgcn_mfma_f32_16x16x32_bf16(al[mt], bh[nt], acc[mt][nt], 0, 0, 0);
                }
            __syncthreads();
        }
        #pragma unroll
        for (int mt = 0; mt < 2; mt++)
            #pragma unroll
            for (int nt = 0; nt < 2; nt++) {
                int n = n0 + wn + nt * 16 + l16;
                #pragma unroll
                for (int r = 0; r < 4; r++) {
                    int m = m0 + wm + mt * 16 + quad * 4 + r;
                    atomicAdd(&z3[(size_t)m * D3 + n], acc[mt][nt][r]);
                }
            }
        return;
    }

    // ---- gemm2 (i8, BK=128): norm3; m2 mask from z2+b2 in LDS ----
    int j = bid - 32;
    signed char* As = (signed char*)smem;
    signed char* Bs = (signed char*)smem + 16384;
    unsigned char* mbuf = (unsigned char*)smem + 32768;  // 512 B
    int m0 = (j & 1) * 128;           // p
    int n0 = ((j >> 1) & 1) * 128;    // d
    int bc = j >> 2;                  // batch
    int l = tid & 63, w = tid >> 6;
    int quad = l >> 4, l16 = l & 15;
    int wm = (w >> 1) * 64, wn = (w & 1) * 64;
    const signed char* Bsrc = qV2 + (size_t)bc * (D * D2);

    {   // fill m2 mask row for this batch
        #pragma unroll
        for (int rr = 0; rr < 2; rr++) {
            int o = tid * 2 + rr;
            float z = z2[(size_t)bc * D2 + o] + b2[o];
            mbuf[o] = (z > 0.f) ? 0xFFu : 0u;
        }
    }
    __syncthreads();

    const signed char* pa[4];
    const signed char* pb[4];
    int lrow = l >> 3, ls = l & 7;
    #pragma unroll
    for (int r = 0; r < 4; r++) {
        int row = r * 32 + w * 8 + lrow;
        int c = (ls + (row & 7)) & 7;
        pa[r] = W3i8 + (size_t)(m0 + row) * D2 + c * 16;
        pb[r] = Bsrc + (size_t)(n0 + row) * D2 + c * 16;
    }
    int aoff[4][2], boff[4][2];
    #pragma unroll
    for (int mt = 0; mt < 4; mt++) {
        int tr = wm + mt * 16 + l16;
        #pragma unroll
        for (int ks = 0; ks < 2; ks++)
            aoff[mt][ks] = tr * 128 + (((ks * 4 + quad) - (tr & 7)) & 7) * 16;
    }
    #pragma unroll
    for (int nt = 0; nt < 4; nt++) {
        int tr = wn + nt * 16 + l16;
        #pragma unroll
        for (int ks = 0; ks < 2; ks++)
            boff[nt][ks] = tr * 128 + (((ks * 4 + quad) - (tr & 7)) & 7) * 16;
    }

    i32x4 acc[4][4];
    #pragma unroll
    for (int i = 0; i < 4; i++)
        #pragma unroll
        for (int jj = 0; jj < 4; jj++) acc[i][jj] = (i32x4)0;

    for (int kk = 0; kk < D2; kk += 128) {
        #pragma unroll
        for (int r = 0; r < 4; r++) {
            gld16(pa[r] + kk, As + r * 4096 + w * 1024);
            gld16(pb[r] + kk, Bs + r * 4096 + w * 1024);
        }
        __syncthreads();
        i32x4 mv0 = *(const i32x4*)(mbuf + kk + quad * 16);
        i32x4 mv1 = *(const i32x4*)(mbuf + kk + 64 + quad * 16);
        #pragma unroll
        for (int ks = 0; ks < 2; ks++) {
            i32x4 mv = ks ? mv1 : mv0;
            i32x4 a[4], bq[4];
            #pragma unroll
            for (int mt = 0; mt < 4; mt++)
                a[mt] = *(const i32x4*)(As + aoff[mt][ks]);
            #pragma unroll
            for (int nt = 0; nt < 4; nt++)
                bq[nt] = (*(const i32x4*)(Bs + boff[nt][ks])) & mv;
            #pragma unroll
            for (int mt = 0; mt < 4; mt++)
                #pragma unroll
                for (int nt = 0; nt < 4; nt++)
                    acc[mt][nt] = __builtin_amdgcn_mfma_i32_16x16x64_i8(
                        a[mt], bq[nt], acc[mt][nt], 0, 0, 0);
        }
        __syncthreads();
    }

    float saCQ[4];
    #pragma unroll
    for (int nt = 0; nt < 4; nt++)
        saCQ[nt] = saq[n0 + wn + nt * 16 + l16] * CQ;

    #pragma unroll
    for (int mt = 0; mt < 4; mt++)
        #pragma unroll
        for (int r = 0; r < 4; r++) {
            float s = 0.f;
            #pragma unroll
            for (int nt = 0; nt < 4; nt++) {
                float v = (float)acc[mt][nt][r] * saCQ[nt];
                s += v * v;
            }
            s += __shfl_down(s, 8, 64);
            s += __shfl_down(s, 4, 64);
            s += __shfl_down(s, 2, 64);
            s += __shfl_down(s, 1, 64);
            if (l16 == 0) {
                int p = m0 + wm + mt * 16 + quad * 4 + r;
                float s3 = s3q[p];
                atomicAdd(&norm3[(size_t)bc * D3 + p], s * s3 * s3);
            }
        }
}

// ---- wave-per-batch k-smallest sum (barrier-free butterfly) ----------------
__global__ __launch_bounds__(256) void k_topk(
    const float* __restrict__ dists,    // [B][D1] dist1 only
    const float* __restrict__ z2, const float* __restrict__ b2,
    const float* __restrict__ norm2,
    const float* __restrict__ z3, const float* __restrict__ b3,
    const float* __restrict__ norm3,
    const int* __restrict__ kp, float* __restrict__ outp) {
    int t = threadIdx.x;
    int wv = t >> 6, lane = t & 63;
    int b = blockIdx.x * 4 + wv;
    float lv[28];
    #pragma unroll
    for (int j = 0; j < 16; j++)
        lv[j] = dists[(size_t)b * D1 + lane + 64 * j];
    #pragma unroll
    for (int j = 16; j < 24; j++) {
        int o = lane + 64 * (j - 16);
        float zz = z2[(size_t)b * D2 + o] + b2[o];
        lv[j] = fabsf(zz) / sqrtf(norm2[(size_t)b * D2 + o]);
    }
    #pragma unroll
    for (int j = 24; j < 28; j++) {
        int p = lane + 64 * (j - 24);
        float zz = z3[(size_t)b * D3 + p] + b3[p];
        lv[j] = fabsf(zz) / sqrtf(norm3[(size_t)b * D3 + p]);
    }
    int k = *kp;
    if (k > NDIST) k = NDIST;
    float sum = 0.f;
    for (int it = 0; it < k; it++) {
        float mv = lv[0]; int mj = 0;
        #pragma unroll
        for (int j = 1; j < 28; j++)
            if (lv[j] < mv) { mv = lv[j]; mj = j; }
        unsigned long long key =
            ((unsigned long long)__float_as_uint(mv) << 32) | (unsigned)(lane * 32 + mj);
        #pragma unroll
        for (int off = 1; off < 64; off <<= 1) {
            unsigned long long o = __shfl_xor(key, off, 64);
            if (o < key) key = o;
        }
        sum += __uint_as_float((unsigned)(key >> 32));
        int wl = (int)((key >> 5) & 63u), wj = (int)(key & 31u);
        if (lane == wl) lv[wj] = FLT_MAX;
    }
    if (lane == 0) atomicAdd(outp, sum);
}

extern "C" void kernel_launch(void* const* d_in, const int* in_sizes, int n_in,
                              void* d_out, int out_size, void* d_ws, size_t ws_size,
                              hipStream_t stream) {
    const float* x  = (const float*)d_in[0];
    const float* W1 = (const float*)d_in[1];
    const float* b1 = (const float*)d_in[2];
    const float* W2 = (const float*)d_in[3];
    const float* b2 = (const float*)d_in[4];
    const float* W3 = (const float*)d_in[5];
    const float* b3 = (const float*)d_in[6];
    const int*   kp = (const int*)d_in[7];
    float* outp = (float*)d_out;

    float* fp = (float*)d_ws;
    float* rn1     = fp;                          fp += D1;
    float* dists   = fp;                          fp += (size_t)B * D1;
    float* saq     = fp;                          fp += D;
    float* sbq     = fp;                          fp += D2;
    float* s3q     = fp;                          fp += D3;
    // zero region: z2 || z3 || norm2 || norm3 (contiguous, 393216 floats)
    float* z2      = fp;                          fp += (size_t)B * D2;
    float* z3      = fp;                          fp += (size_t)B * D3;
    float* norm2   = fp;                          fp += (size_t)B * D2;
    float* norm3   = fp;                          fp += (size_t)B * D3;
    unsigned short* up = (unsigned short*)fp;
    unsigned short* W2hi  = up;  up += (size_t)D2 * D1;
    unsigned short* W2lo  = up;  up += (size_t)D2 * D1;
    unsigned short* W3hi  = up;  up += (size_t)D3 * D2;
    unsigned short* W3lo  = up;  up += (size_t)D3 * D2;
    unsigned short* xhi   = up;  up += (size_t)B * D;
    unsigned short* xlo   = up;  up += (size_t)B * D;
    unsigned short* W1hi  = up;  up += (size_t)D1 * D;
    unsigned short* W1lo  = up;  up += (size_t)D1 * D;
    unsigned short* h1hi  = up;  up += (size_t)B * D1;
    unsigned short* h1lo  = up;  up += (size_t)B * D1;
    signed char*    cp = (signed char*)up;
    signed char*    W1Ti8 = cp;  cp += (size_t)D * D1;
    signed char*    W2i8  = cp;  cp += (size_t)D2 * D1;
    signed char*    W3i8  = cp;  cp += (size_t)D3 * D2;
    unsigned char*  m1q   = (unsigned char*)cp;  cp += (size_t)B * D1;
    signed char*    qV2   = cp;   // full 256-batch (33.5 MB; ws proven since R10)

    k_prepA<<<576, 256, 0, stream>>>(x, W1, xhi, xlo, W1hi, W1lo, rn1);

    // l1 gemm (64) + zeros (384) + W2/W3 splits (640) + i8 quants (224)
    k_l1p<<<1312, 256, 0, stream>>>(W1, W2, W3, xhi, xlo, W1hi, W1lo, b1, rn1,
                                    dists, m1q, h1hi, h1lo,
                                    z2, outp, W2hi, W2lo, W3hi, W3lo,
                                    W1Ti8, saq, W2i8, sbq, W3i8, s3q);

    // l2a (128) || gemm1 (2048)
    k_big1<<<2176, 256, 0, stream>>>(h1hi, h1lo, W2hi, W2lo, z2,
                                     W1Ti8, W2i8, m1q, saq, sbq, qV2, norm2);

    // l3a z2-direct (32) || gemm2 mask-from-LDS (1024)
    k_big2<<<1056, 256, 0, stream>>>(z2, b2, W3hi, W3lo, z3,
                                     W3i8, qV2, saq, s3q, norm3);

    k_topk<<<B / 4, 256, 0, stream>>>(dists, z2, b2, norm2, z3, b3, norm3, kp, outp);
}

// Round 16
// 175.402 us; speedup vs baseline: 1.1125x; 1.0141x over previous
//
#include <hip/hip_runtime.h>
#include <math.h>
#include <float.h>

#define B   256
#define D   256
#define D1  1024
#define D2  512
#define D3  256
#define NDIST (D1 + D2 + D3)   // 1792
#define CQ  2.0f               // qV2 static scale multiplier (step = sa[d]*CQ)

typedef __attribute__((ext_vector_type(8))) short short8;
typedef __attribute__((ext_vector_type(4))) float f32x4;
typedef __attribute__((ext_vector_type(4))) int   i32x4;

__device__ __forceinline__ float waveReduceSum(float v) {
    #pragma unroll
    for (int off = 32; off > 0; off >>= 1)
        v += __shfl_down(v, off, 64);
    return v;
}
__device__ __forceinline__ float waveReduceMax(float v) {
    #pragma unroll
    for (int off = 32; off > 0; off >>= 1)
        v = fmaxf(v, __shfl_down(v, off, 64));
    return v;
}
__device__ __forceinline__ unsigned short f2bf(float f) {
    unsigned int u = __float_as_uint(f);
    u = (u + 0x7FFFu + ((u >> 16) & 1u)) >> 16;   // RNE
    return (unsigned short)u;
}
__device__ __forceinline__ float bf2f(unsigned short h) {
    return __uint_as_float(((unsigned int)h) << 16);
}
__device__ __forceinline__ void gld16(const void* g, void* l) {
    __builtin_amdgcn_global_load_lds(
        (const __attribute__((address_space(1))) unsigned int*)g,
        (__attribute__((address_space(3))) unsigned int*)l, 16, 0, 0);
}
__device__ __forceinline__ int swz_src(int row, int lane) {
    return ((lane & 3) + ((row >> 1) & 3)) & 3;
}
__device__ __forceinline__ int swz_frag(int row, int quad) {
    return row * 32 + (((quad - ((row >> 1) & 3)) & 3) * 8);
}

__device__ __forceinline__ void split_job(const float* src, unsigned short* hi,
                                          unsigned short* lo, int off) {
    float4 v = *(const float4*)(src + off);
    ushort4 h, l;
    h.x = f2bf(v.x); l.x = f2bf(v.x - bf2f(h.x));
    h.y = f2bf(v.y); l.y = f2bf(v.y - bf2f(h.y));
    h.z = f2bf(v.z); l.z = f2bf(v.z - bf2f(h.z));
    h.w = f2bf(v.w); l.w = f2bf(v.w - bf2f(h.w));
    *(ushort4*)(hi + off) = h;
    *(ushort4*)(lo + off) = l;
}

// load 8 fp32, split to bf16 hi/lo short8
__device__ __forceinline__ void split8(const float* p, short8& h8, short8& l8) {
    float4 a = *(const float4*)(p);
    float4 b = *(const float4*)(p + 4);
    float hv[8] = { a.x, a.y, a.z, a.w, b.x, b.y, b.z, b.w };
    #pragma unroll
    for (int q = 0; q < 8; q++) {
        unsigned short hh = f2bf(hv[q]);
        h8[q] = (short)hh;
        l8[q] = (short)f2bf(hv[q] - bf2f(hh));
    }
}

// ---- compensated bf16 MFMA mainloop, 64x64 tile, K range [k0, k0+KL) -------
template <int KD, int KL>
__device__ __forceinline__ void mfma3_64(
    const unsigned short* __restrict__ Ahi, const unsigned short* __restrict__ Alo,
    const unsigned short* __restrict__ Bhi, const unsigned short* __restrict__ Blo,
    int m0, int n0, int k0, unsigned short* sm, f32x4 acc[2][2]) {
    int tid = threadIdx.x;
    int l = tid & 63, w = tid >> 6;
    int rsub = l >> 2;
    int quad = l >> 4, l16 = l & 15;
    int wm = (w >> 1) * 32, wn = (w & 1) * 32;
    unsigned short* sAh = sm;
    unsigned short* sAl = sm + 2048;
    unsigned short* sBh = sm + 4096;
    unsigned short* sBl = sm + 6144;
    ptrdiff_t dA = Alo - Ahi, dB = Blo - Bhi;
    int rloc = w * 16 + rsub;
    int c = swz_src(rloc, l);
    const unsigned short* pa = Ahi + (size_t)(m0 + rloc) * KD + k0 + c * 8;
    const unsigned short* pb = Bhi + (size_t)(n0 + rloc) * KD + k0 + c * 8;
    int aoff[2], boff[2];
    #pragma unroll
    for (int mt = 0; mt < 2; mt++) aoff[mt] = swz_frag(wm + mt * 16 + l16, quad);
    #pragma unroll
    for (int nt = 0; nt < 2; nt++) boff[nt] = swz_frag(wn + nt * 16 + l16, quad);
    for (int kk = 0; kk < KL; kk += 32) {
        gld16(pa + kk,      sAh + w * 512);
        gld16(pa + dA + kk, sAl + w * 512);
        gld16(pb + kk,      sBh + w * 512);
        gld16(pb + dB + kk, sBl + w * 512);
        __syncthreads();
        short8 ah[2], al[2], bh[2], bl[2];
        #pragma unroll
        for (int mt = 0; mt < 2; mt++) {
            ah[mt] = *(const short8*)(sAh + aoff[mt]);
            al[mt] = *(const short8*)(sAl + aoff[mt]);
        }
        #pragma unroll
        for (int nt = 0; nt < 2; nt++) {
            bh[nt] = *(const short8*)(sBh + boff[nt]);
            bl[nt] = *(const short8*)(sBl + boff[nt]);
        }
        #pragma unroll
        for (int mt = 0; mt < 2; mt++)
            #pragma unroll
            for (int nt = 0; nt < 2; nt++) {
                acc[mt][nt] = __builtin_amdgcn_mfma_f32_16x16x32_bf16(ah[mt], bh[nt], acc[mt][nt], 0, 0, 0);
                acc[mt][nt] = __builtin_amdgcn_mfma_f32_16x16x32_bf16(ah[mt], bl[nt], acc[mt][nt], 0, 0, 0);
                acc[mt][nt] = __builtin_amdgcn_mfma_f32_16x16x32_bf16(al[mt], bh[nt], acc[mt][nt], 0, 0, 0);
            }
        __syncthreads();
    }
}

// ---- dispatch 1: l1 gemm (fp32 direct staging) + zeros + splits + quants ---
__global__ __launch_bounds__(256) void k_l1p(
    const float* __restrict__ x, const float* __restrict__ W1,
    const float* __restrict__ W2, const float* __restrict__ W3,
    const float* __restrict__ b1,
    float* __restrict__ dists, unsigned char* __restrict__ m1q,
    unsigned short* __restrict__ h1hi, unsigned short* __restrict__ h1lo,
    float* __restrict__ zeros, float* __restrict__ outp,
    unsigned short* __restrict__ W2hi, unsigned short* __restrict__ W2lo,
    unsigned short* __restrict__ W3hi, unsigned short* __restrict__ W3lo,
    signed char* __restrict__ W1Ti8, float* __restrict__ saq,
    signed char* __restrict__ W2i8,  float* __restrict__ sbq,
    signed char* __restrict__ W3i8,  float* __restrict__ s3q,
    float* __restrict__ rn1) {
    __shared__ __align__(16) unsigned short sm[8192];
    int blk = blockIdx.x;
    int t = threadIdx.x;

    if (blk < 64) {          // l1: z1 GEMM; A=x, B=W1 staged fp32->hi/lo
        unsigned short* sAh = sm;
        unsigned short* sAl = sm + 2048;
        unsigned short* sBh = sm + 4096;
        unsigned short* sBl = sm + 6144;
        int m0 = (blk & 3) * 64, n0 = (blk >> 2) * 64;
        int l = t & 63, w = t >> 6;
        int rsub = l >> 2;
        int quad = l >> 4, l16 = l & 15;
        int wm = (w >> 1) * 32, wn = (w & 1) * 32;
        int rloc = w * 16 + rsub;
        int c = swz_src(rloc, l);
        const float* pax = x + (size_t)(m0 + rloc) * D + c * 8;
        const float* pbw = W1 + (size_t)(n0 + rloc) * D + c * 8;
        int aoff[2], boff[2];
        #pragma unroll
        for (int mt = 0; mt < 2; mt++) aoff[mt] = swz_frag(wm + mt * 16 + l16, quad);
        #pragma unroll
        for (int nt = 0; nt < 2; nt++) boff[nt] = swz_frag(wn + nt * 16 + l16, quad);
        int wrA = w * 512 + l * 8;
        f32x4 acc[2][2] = {};
        for (int kk = 0; kk < D; kk += 32) {
            short8 ha, la, hb, lb;
            split8(pax + kk, ha, la);
            split8(pbw + kk, hb, lb);
            *(short8*)(sAh + wrA) = ha;
            *(short8*)(sAl + wrA) = la;
            *(short8*)(sBh + wrA) = hb;
            *(short8*)(sBl + wrA) = lb;
            __syncthreads();
            short8 ah[2], al[2], bh[2], bl[2];
            #pragma unroll
            for (int mt = 0; mt < 2; mt++) {
                ah[mt] = *(const short8*)(sAh + aoff[mt]);
                al[mt] = *(const short8*)(sAl + aoff[mt]);
            }
            #pragma unroll
            for (int nt = 0; nt < 2; nt++) {
                bh[nt] = *(const short8*)(sBh + boff[nt]);
                bl[nt] = *(const short8*)(sBl + boff[nt]);
            }
            #pragma unroll
            for (int mt = 0; mt < 2; mt++)
                #pragma unroll
                for (int nt = 0; nt < 2; nt++) {
                    acc[mt][nt] = __builtin_amdgcn_mfma_f32_16x16x32_bf16(ah[mt], bh[nt], acc[mt][nt], 0, 0, 0);
                    acc[mt][nt] = __builtin_amdgcn_mfma_f32_16x16x32_bf16(ah[mt], bl[nt], acc[mt][nt], 0, 0, 0);
                    acc[mt][nt] = __builtin_amdgcn_mfma_f32_16x16x32_bf16(al[mt], bh[nt], acc[mt][nt], 0, 0, 0);
                }
            __syncthreads();
        }
        #pragma unroll
        for (int mt = 0; mt < 2; mt++)
            #pragma unroll
            for (int nt = 0; nt < 2; nt++) {
                int n = n0 + wn + nt * 16 + l16;
                float bv = b1[n];
                #pragma unroll
                for (int r = 0; r < 4; r++) {
                    int m = m0 + wm + mt * 16 + quad * 4 + r;
                    float z = acc[mt][nt][r] + bv;
                    size_t idx = (size_t)m * D1 + n;
                    dists[idx] = fabsf(z);          // rn1 division deferred to topk
                    m1q[idx] = (z > 0.f) ? 0xFFu : 0u;
                    float h = z > 0.f ? z : 0.f;
                    unsigned short hh = f2bf(h);
                    h1hi[idx] = hh;
                    h1lo[idx] = f2bf(h - bf2f(hh));
                }
            }
        return;
    }
    if (blk < 448) {                                   // zero region (float4)
        if (blk == 64 && t == 0) outp[0] = 0.f;
        int i4 = (blk - 64) * 1024 + t * 4;
        *(float4*)(zeros + i4) = make_float4(0.f, 0.f, 0.f, 0.f);
        return;
    }
    if (blk < 960) {                                   // W2 split (524288)
        split_job(W2, W2hi, W2lo, (blk - 448) * 1024 + t * 4);
        return;
    }
    if (blk < 1088) {                                  // W3 split (131072)
        split_job(W3, W3hi, W3lo, (blk - 960) * 1024 + t * 4);
        return;
    }
    if (blk < 1120) {                                  // W1 col quant -> W1Ti8
        int ty = t >> 5, tx = t & 31;
        int d = (blk - 1088) * 8 + ty;
        float m = 0.f;
        for (int i = tx; i < D1; i += 32) m = fmaxf(m, fabsf(W1[(size_t)i * D + d]));
        #pragma unroll
        for (int off = 16; off > 0; off >>= 1) m = fmaxf(m, __shfl_down(m, off, 32));
        m = __shfl(m, 0, 32);
        m = fmaxf(m, 1e-20f);
        if (tx == 0) saq[d] = m / 127.f;
        float inv = 127.f / m;
        for (int i = tx; i < D1; i += 32) {
            int q = __float2int_rn(W1[(size_t)i * D + d] * inv);
            W1Ti8[(size_t)d * D1 + i] = (signed char)q;
        }
        return;
    }
    if (blk < 1248) {                                  // W2 row quant
        int o = (blk - 1120) * 4 + (t >> 6);
        int l = t & 63;
        const float* row = W2 + (size_t)o * D1;
        float m = 0.f;
        for (int tt = l; tt < D1; tt += 64) m = fmaxf(m, fabsf(row[tt]));
        m = waveReduceMax(m);
        m = __shfl(m, 0, 64);
        m = fmaxf(m, 1e-20f);
        if (l == 0) sbq[o] = m / 127.f;
        float inv = 127.f / m;
        for (int tt = l; tt < D1; tt += 64)
            W2i8[(size_t)o * D1 + tt] = (signed char)__float2int_rn(row[tt] * inv);
        return;
    }
    if (blk < 1312) {                                  // W3 row quant (64 blks)
        int p = (blk - 1248) * 4 + (t >> 6);
        int l = t & 63;
        const float* row = W3 + (size_t)p * D2;
        float m = 0.f;
        for (int tt = l; tt < D2; tt += 64) m = fmaxf(m, fabsf(row[tt]));
        m = waveReduceMax(m);
        m = __shfl(m, 0, 64);
        m = fmaxf(m, 1e-20f);
        if (l == 0) s3q[p] = m / 127.f;
        float inv = 127.f / m;
        for (int tt = l; tt < D2; tt += 64)
            W3i8[(size_t)p * D2 + tt] = (signed char)__float2int_rn(row[tt] * inv);
        return;
    }
    {                                                  // rn1 (256 blks, topk-only)
        int gw = (blk - 1312) * 4 + (t >> 6);
        int lane = t & 63;
        const float* row = W1 + (size_t)gw * D;
        float s = 0.f;
        for (int tt = lane; tt < D; tt += 64) { float v = row[tt]; s += v * v; }
        s = waveReduceSum(s);
        if (lane == 0) rn1[gw] = sqrtf(s);
    }
}

// ---- merged dispatch 2: l2a (blocks 0..127) || gemm1 (128..2175) -----------
__global__ __launch_bounds__(256) void k_big1(
    const unsigned short* __restrict__ h1hi, const unsigned short* __restrict__ h1lo,
    const unsigned short* __restrict__ W2hi, const unsigned short* __restrict__ W2lo,
    float* __restrict__ z2,
    const signed char* __restrict__ W1Ti8,   // [256][1024]  A rows (d)
    const signed char* __restrict__ W2i8,    // [512][1024]  B rows (o)
    const unsigned char* __restrict__ m1q,   // [B][1024]
    const float* __restrict__ saq,           // [256]
    const float* __restrict__ sbq,           // [512]
    signed char* __restrict__ qV2,           // [256][256][512] (d-major)
    float* __restrict__ norm2) {             // [B][512]
    __shared__ __align__(16) unsigned char smem[32768];
    int bid = blockIdx.x;

    if (bid < 128) {
        // ---- l2a: split-K partial z2 (atomic; bias folded downstream) ----
        unsigned short* sm = (unsigned short*)smem;
        int m0 = (bid & 3) * 64, n0 = ((bid >> 2) & 7) * 64, k0 = (bid >> 5) * 256;
        f32x4 acc[2][2] = {};
        mfma3_64<D1, 256>(h1hi, h1lo, W2hi, W2lo, m0, n0, k0, sm, acc);
        int l = threadIdx.x & 63, w = threadIdx.x >> 6;
        int quad = l >> 4, l16 = l & 15;
        int wm = (w >> 1) * 32, wn = (w & 1) * 32;
        #pragma unroll
        for (int mt = 0; mt < 2; mt++)
            #pragma unroll
            for (int nt = 0; nt < 2; nt++) {
                int n = n0 + wn + nt * 16 + l16;
                #pragma unroll
                for (int r = 0; r < 4; r++) {
                    int m = m0 + wm + mt * 16 + quad * 4 + r;
                    atomicAdd(&z2[(size_t)m * D2 + n], acc[mt][nt][r]);
                }
            }
        return;
    }

    // ---- gemm1 (i8, BK=128, M=d/N=o, mask on A; direct-store epilogue) ----
    int j = bid - 128;
    signed char* As = (signed char*)smem;
    signed char* Bs = (signed char*)smem + 16384;
    int m0 = (j & 1) * 128;           // d
    int o0 = ((j >> 1) & 3) * 128;    // o
    int b = j >> 3;                   // batch
    int tid = threadIdx.x;
    int l = tid & 63, w = tid >> 6;
    int quad = l >> 4, l16 = l & 15;
    int wm = (w >> 1) * 64, wn = (w & 1) * 64;
    const unsigned char* mrow = m1q + (size_t)b * D1;

    const signed char* pa[4];
    const signed char* pb[4];
    int lrow = l >> 3, ls = l & 7;
    #pragma unroll
    for (int r = 0; r < 4; r++) {
        int row = r * 32 + w * 8 + lrow;
        int c = (ls + (row & 7)) & 7;
        pa[r] = W1Ti8 + (size_t)(m0 + row) * D1 + c * 16;
        pb[r] = W2i8 + (size_t)(o0 + row) * D1 + c * 16;
    }
    int aoff[4][2], boff[4][2];
    #pragma unroll
    for (int mt = 0; mt < 4; mt++) {
        int tr = wm + mt * 16 + l16;
        #pragma unroll
        for (int ks = 0; ks < 2; ks++)
            aoff[mt][ks] = tr * 128 + (((ks * 4 + quad) - (tr & 7)) & 7) * 16;
    }
    #pragma unroll
    for (int nt = 0; nt < 4; nt++) {
        int tr = wn + nt * 16 + l16;
        #pragma unroll
        for (int ks = 0; ks < 2; ks++)
            boff[nt][ks] = tr * 128 + (((ks * 4 + quad) - (tr & 7)) & 7) * 16;
    }

    i32x4 acc[4][4];
    #pragma unroll
    for (int i = 0; i < 4; i++)
        #pragma unroll
        for (int jj = 0; jj < 4; jj++) acc[i][jj] = (i32x4)0;

    for (int kk = 0; kk < D1; kk += 128) {
        #pragma unroll
        for (int r = 0; r < 4; r++) {
            gld16(pa[r] + kk, As + r * 4096 + w * 1024);
            gld16(pb[r] + kk, Bs + r * 4096 + w * 1024);
        }
        i32x4 mv0 = *(const i32x4*)(mrow + kk + quad * 16);
        i32x4 mv1 = *(const i32x4*)(mrow + kk + 64 + quad * 16);
        __syncthreads();
        #pragma unroll
        for (int ks = 0; ks < 2; ks++) {
            i32x4 mv = ks ? mv1 : mv0;
            i32x4 a[4], bq[4];
            #pragma unroll
            for (int mt = 0; mt < 4; mt++)
                a[mt] = (*(const i32x4*)(As + aoff[mt][ks])) & mv;
            #pragma unroll
            for (int nt = 0; nt < 4; nt++)
                bq[nt] = *(const i32x4*)(Bs + boff[nt][ks]);
            #pragma unroll
            for (int mt = 0; mt < 4; mt++)
                #pragma unroll
                for (int nt = 0; nt < 4; nt++)
                    acc[mt][nt] = __builtin_amdgcn_mfma_i32_16x16x64_i8(
                        a[mt], bq[nt], acc[mt][nt], 0, 0, 0);
        }
        __syncthreads();
    }

    float sad[4][4];
    #pragma unroll
    for (int mt = 0; mt < 4; mt++)
        #pragma unroll
        for (int r = 0; r < 4; r++)
            sad[mt][r] = saq[m0 + wm + mt * 16 + quad * 4 + r];
    float sbv[4], sbdq[4];
    #pragma unroll
    for (int nt = 0; nt < 4; nt++) {
        sbv[nt] = sbq[o0 + wn + nt * 16 + l16];
        sbdq[nt] = sbv[nt] * (1.0f / CQ);
    }

    // norm2[o] += sum_d V2^2
    #pragma unroll
    for (int nt = 0; nt < 4; nt++) {
        float s = 0.f;
        #pragma unroll
        for (int mt = 0; mt < 4; mt++)
            #pragma unroll
            for (int r = 0; r < 4; r++) {
                float v = (float)acc[mt][nt][r] * sad[mt][r] * sbv[nt];
                s += v * v;
            }
        s += __shfl_down(s, 32, 64);
        s += __shfl_down(s, 16, 64);
        if (l < 16)
            atomicAdd(&norm2[(size_t)b * D2 + o0 + wn + nt * 16 + l], s);
    }

    // qV2[d][o] int8 direct byte stores (0 conflicts)
    signed char* qb = qV2 + (size_t)b * (D * D2);
    #pragma unroll
    for (int mt = 0; mt < 4; mt++) {
        int dbase = m0 + wm + mt * 16 + quad * 4;
        #pragma unroll
        for (int r = 0; r < 4; r++)
            #pragma unroll
            for (int nt = 0; nt < 4; nt++) {
                int o = o0 + wn + nt * 16 + l16;
                int qi = __float2int_rn((float)acc[mt][nt][r] * sbdq[nt]);
                qi = max(-127, min(127, qi));
                qb[(size_t)(dbase + r) * D2 + o] = (signed char)qi;
            }
    }
}

// ---- merged dispatch 3: l3a z2-direct (0..31) || gemm2 (32..1055) ----------
__global__ __launch_bounds__(256) void k_big2(
    const float* __restrict__ z2,            // [B][512] (bias NOT applied)
    const float* __restrict__ b2,            // [512]
    const unsigned short* __restrict__ W3hi, const unsigned short* __restrict__ W3lo,
    float* __restrict__ z3,
    const signed char* __restrict__ W3i8,    // [256][512]
    const signed char* __restrict__ qV2,     // [256][256][512]
    const float* __restrict__ saq,           // [256]
    const float* __restrict__ s3q,           // [256]
    float* __restrict__ norm3) {             // [B][256]
    __shared__ __align__(16) unsigned char smem[33280];  // 32K tiles + 512B mask
    int bid = blockIdx.x;
    int tid = threadIdx.x;

    if (bid < 32) {
        // ---- l3a: split-K partial z3; A = relu(z2+b2) hi/lo computed inline
        unsigned short* sAh = (unsigned short*)smem;
        unsigned short* sAl = sAh + 2048;
        unsigned short* sBh = sAh + 4096;
        unsigned short* sBl = sAh + 6144;
        int m0 = (bid & 3) * 64, n0 = ((bid >> 2) & 3) * 64, k0 = (bid >> 4) * 256;
        int l = tid & 63, w = tid >> 6;
        int rsub = l >> 2;
        int quad = l >> 4, l16 = l & 15;
        int wm = (w >> 1) * 32, wn = (w & 1) * 32;
        int rloc = w * 16 + rsub;
        int c = swz_src(rloc, l);
        const float* pz  = z2 + (size_t)(m0 + rloc) * D2 + k0 + c * 8;
        const float* pbi = b2 + k0 + c * 8;
        const unsigned short* pb = W3hi + (size_t)(n0 + rloc) * D2 + k0 + c * 8;
        ptrdiff_t dB = W3lo - W3hi;
        int aoff[2], boff[2];
        #pragma unroll
        for (int mt = 0; mt < 2; mt++) aoff[mt] = swz_frag(wm + mt * 16 + l16, quad);
        #pragma unroll
        for (int nt = 0; nt < 2; nt++) boff[nt] = swz_frag(wn + nt * 16 + l16, quad);
        int wrA = w * 512 + l * 8;
        f32x4 acc[2][2] = {};
        for (int kk = 0; kk < 256; kk += 32) {
            gld16(pb + kk,      sBh + w * 512);
            gld16(pb + dB + kk, sBl + w * 512);
            float4 za = *(const float4*)(pz + kk);
            float4 zb = *(const float4*)(pz + kk + 4);
            float4 ba = *(const float4*)(pbi + kk);
            float4 bb = *(const float4*)(pbi + kk + 4);
            float hv[8] = { za.x + ba.x, za.y + ba.y, za.z + ba.z, za.w + ba.w,
                            zb.x + bb.x, zb.y + bb.y, zb.z + bb.z, zb.w + bb.w };
            short8 h8, l8;
            #pragma unroll
            for (int q2 = 0; q2 < 8; q2++) {
                float h = hv[q2] > 0.f ? hv[q2] : 0.f;
                unsigned short hh = f2bf(h);
                h8[q2] = (short)hh;
                l8[q2] = (short)f2bf(h - bf2f(hh));
            }
            *(short8*)(sAh + wrA) = h8;
            *(short8*)(sAl + wrA) = l8;
            __syncthreads();
            short8 ah[2], al[2], bh[2], bl[2];
            #pragma unroll
            for (int mt = 0; mt < 2; mt++) {
                ah[mt] = *(const short8*)(sAh + aoff[mt]);
                al[mt] = *(const short8*)(sAl + aoff[mt]);
            }
            #pragma unroll
            for (int nt = 0; nt < 2; nt++) {
                bh[nt] = *(const short8*)(sBh + boff[nt]);
                bl[nt] = *(const short8*)(sBl + boff[nt]);
            }
            #pragma unroll
            for (int mt = 0; mt < 2; mt++)
                #pragma unroll
                for (int nt = 0; nt < 2; nt++) {
                    acc[mt][nt] = __builtin_amdgcn_mfma_f32_16x16x32_bf16(ah[mt], bh[nt], acc[mt][nt], 0, 0, 0);
                    acc[mt][nt] = __builtin_amdgcn_mfma_f32_16x16x32_bf16(ah[mt], bl[nt], acc[mt][nt], 0, 0, 0);
                    acc[mt][nt] = __builtin_amdgcn_mfma_f32_16x16x32_bf16(al[mt], bh[nt], acc[mt][nt], 0, 0, 0);
                }
            __syncthreads();
        }
        #pragma unroll
        for (int mt = 0; mt < 2; mt++)
            #pragma unroll
            for (int nt = 0; nt < 2; nt++) {
                int n = n0 + wn + nt * 16 + l16;
                #pragma unroll
                for (int r = 0; r < 4; r++) {
                    int m = m0 + wm + mt * 16 + quad * 4 + r;
                    atomicAdd(&z3[(size_t)m * D3 + n], acc[mt][nt][r]);
                }
            }
        return;
    }

    // ---- gemm2 (i8, BK=128): norm3; m2 mask from z2+b2 in LDS ----
    int j = bid - 32;
    signed char* As = (signed char*)smem;
    signed char* Bs = (signed char*)smem + 16384;
    unsigned char* mbuf = (unsigned char*)smem + 32768;  // 512 B
    int m0 = (j & 1) * 128;           // p
    int n0 = ((j >> 1) & 1) * 128;    // d
    int bc = j >> 2;                  // batch
    int l = tid & 63, w = tid >> 6;
    int quad = l >> 4, l16 = l & 15;
    int wm = (w >> 1) * 64, wn = (w & 1) * 64;
    const signed char* Bsrc = qV2 + (size_t)bc * (D * D2);

    {   // fill m2 mask row for this batch
        #pragma unroll
        for (int rr = 0; rr < 2; rr++) {
            int o = tid * 2 + rr;
            float z = z2[(size_t)bc * D2 + o] + b2[o];
            mbuf[o] = (z > 0.f) ? 0xFFu : 0u;
        }
    }
    __syncthreads();

    const signed char* pa[4];
    const signed char* pb[4];
    int lrow = l >> 3, ls = l & 7;
    #pragma unroll
    for (int r = 0; r < 4; r++) {
        int row = r * 32 + w * 8 + lrow;
        int c = (ls + (row & 7)) & 7;
        pa[r] = W3i8 + (size_t)(m0 + row) * D2 + c * 16;
        pb[r] = Bsrc + (size_t)(n0 + row) * D2 + c * 16;
    }
    int aoff[4][2], boff[4][2];
    #pragma unroll
    for (int mt = 0; mt < 4; mt++) {
        int tr = wm + mt * 16 + l16;
        #pragma unroll
        for (int ks = 0; ks < 2; ks++)
            aoff[mt][ks] = tr * 128 + (((ks * 4 + quad) - (tr & 7)) & 7) * 16;
    }
    #pragma unroll
    for (int nt = 0; nt < 4; nt++) {
        int tr = wn + nt * 16 + l16;
        #pragma unroll
        for (int ks = 0; ks < 2; ks++)
            boff[nt][ks] = tr * 128 + (((ks * 4 + quad) - (tr & 7)) & 7) * 16;
    }

    i32x4 acc[4][4];
    #pragma unroll
    for (int i = 0; i < 4; i++)
        #pragma unroll
        for (int jj = 0; jj < 4; jj++) acc[i][jj] = (i32x4)0;

    for (int kk = 0; kk < D2; kk += 128) {
        #pragma unroll
        for (int r = 0; r < 4; r++) {
            gld16(pa[r] + kk, As + r * 4096 + w * 1024);
            gld16(pb[r] + kk, Bs + r * 4096 + w * 1024);
        }
        __syncthreads();
        i32x4 mv0 = *(const i32x4*)(mbuf + kk + quad * 16);
        i32x4 mv1 = *(const i32x4*)(mbuf + kk + 64 + quad * 16);
        #pragma unroll
        for (int ks = 0; ks < 2; ks++) {
            i32x4 mv = ks ? mv1 : mv0;
            i32x4 a[4], bq[4];
            #pragma unroll
            for (int mt = 0; mt < 4; mt++)
                a[mt] = *(const i32x4*)(As + aoff[mt][ks]);
            #pragma unroll
            for (int nt = 0; nt < 4; nt++)
                bq[nt] = (*(const i32x4*)(Bs + boff[nt][ks])) & mv;
            #pragma unroll
            for (int mt = 0; mt < 4; mt++)
                #pragma unroll
                for (int nt = 0; nt < 4; nt++)
                    acc[mt][nt] = __builtin_amdgcn_mfma_i32_16x16x64_i8(
                        a[mt], bq[nt], acc[mt][nt], 0, 0, 0);
        }
        __syncthreads();
    }

    float saCQ[4];
    #pragma unroll
    for (int nt = 0; nt < 4; nt++)
        saCQ[nt] = saq[n0 + wn + nt * 16 + l16] * CQ;

    #pragma unroll
    for (int mt = 0; mt < 4; mt++)
        #pragma unroll
        for (int r = 0; r < 4; r++) {
            float s = 0.f;
            #pragma unroll
            for (int nt = 0; nt < 4; nt++) {
                float v = (float)acc[mt][nt][r] * saCQ[nt];
                s += v * v;
            }
            s += __shfl_down(s, 8, 64);
            s += __shfl_down(s, 4, 64);
            s += __shfl_down(s, 2, 64);
            s += __shfl_down(s, 1, 64);
            if (l16 == 0) {
                int p = m0 + wm + mt * 16 + quad * 4 + r;
                float s3 = s3q[p];
                atomicAdd(&norm3[(size_t)bc * D3 + p], s * s3 * s3);
            }
        }
}

// ---- wave-per-batch k-smallest sum (dist1 = |z1|/rn1 computed inline) ------
__global__ __launch_bounds__(256) void k_topk(
    const float* __restrict__ dists,    // [B][D1] |z1| only
    const float* __restrict__ rn1,      // [D1]
    const float* __restrict__ z2, const float* __restrict__ b2,
    const float* __restrict__ norm2,
    const float* __restrict__ z3, const float* __restrict__ b3,
    const float* __restrict__ norm3,
    const int* __restrict__ kp, float* __restrict__ outp) {
    int t = threadIdx.x;
    int wv = t >> 6, lane = t & 63;
    int b = blockIdx.x * 4 + wv;
    float lv[28];
    #pragma unroll
    for (int j = 0; j < 16; j++) {
        int n = lane + 64 * j;
        lv[j] = dists[(size_t)b * D1 + n] / rn1[n];
    }
    #pragma unroll
    for (int j = 16; j < 24; j++) {
        int o = lane + 64 * (j - 16);
        float zz = z2[(size_t)b * D2 + o] + b2[o];
        lv[j] = fabsf(zz) / sqrtf(norm2[(size_t)b * D2 + o]);
    }
    #pragma unroll
    for (int j = 24; j < 28; j++) {
        int p = lane + 64 * (j - 24);
        float zz = z3[(size_t)b * D3 + p] + b3[p];
        lv[j] = fabsf(zz) / sqrtf(norm3[(size_t)b * D3 + p]);
    }
    int k = *kp;
    if (k > NDIST) k = NDIST;
    float sum = 0.f;
    for (int it = 0; it < k; it++) {
        float mv = lv[0]; int mj = 0;
        #pragma unroll
        for (int j = 1; j < 28; j++)
            if (lv[j] < mv) { mv = lv[j]; mj = j; }
        unsigned long long key =
            ((unsigned long long)__float_as_uint(mv) << 32) | (unsigned)(lane * 32 + mj);
        #pragma unroll
        for (int off = 1; off < 64; off <<= 1) {
            unsigned long long o = __shfl_xor(key, off, 64);
            if (o < key) key = o;
        }
        sum += __uint_as_float((unsigned)(key >> 32));
        int wl = (int)((key >> 5) & 63u), wj = (int)(key & 31u);
        if (lane == wl) lv[wj] = FLT_MAX;
    }
    if (lane == 0) atomicAdd(outp, sum);
}

extern "C" void kernel_launch(void* const* d_in, const int* in_sizes, int n_in,
                              void* d_out, int out_size, void* d_ws, size_t ws_size,
                              hipStream_t stream) {
    const float* x  = (const float*)d_in[0];
    const float* W1 = (const float*)d_in[1];
    const float* b1 = (const float*)d_in[2];
    const float* W2 = (const float*)d_in[3];
    const float* b2 = (const float*)d_in[4];
    const float* W3 = (const float*)d_in[5];
    const float* b3 = (const float*)d_in[6];
    const int*   kp = (const int*)d_in[7];
    float* outp = (float*)d_out;

    float* fp = (float*)d_ws;
    float* rn1     = fp;                          fp += D1;
    float* dists   = fp;                          fp += (size_t)B * D1;
    float* saq     = fp;                          fp += D;
    float* sbq     = fp;                          fp += D2;
    float* s3q     = fp;                          fp += D3;
    // zero region: z2 || z3 || norm2 || norm3 (contiguous, 393216 floats)
    float* z2      = fp;                          fp += (size_t)B * D2;
    float* z3      = fp;                          fp += (size_t)B * D3;
    float* norm2   = fp;                          fp += (size_t)B * D2;
    float* norm3   = fp;                          fp += (size_t)B * D3;
    unsigned short* up = (unsigned short*)fp;
    unsigned short* W2hi  = up;  up += (size_t)D2 * D1;
    unsigned short* W2lo  = up;  up += (size_t)D2 * D1;
    unsigned short* W3hi  = up;  up += (size_t)D3 * D2;
    unsigned short* W3lo  = up;  up += (size_t)D3 * D2;
    unsigned short* h1hi  = up;  up += (size_t)B * D1;
    unsigned short* h1lo  = up;  up += (size_t)B * D1;
    signed char*    cp = (signed char*)up;
    signed char*    W1Ti8 = cp;  cp += (size_t)D * D1;
    signed char*    W2i8  = cp;  cp += (size_t)D2 * D1;
    signed char*    W3i8  = cp;  cp += (size_t)D3 * D2;
    unsigned char*  m1q   = (unsigned char*)cp;  cp += (size_t)B * D1;
    signed char*    qV2   = cp;   // full 256-batch (33.5 MB; ws proven since R10)

    // l1 gemm (64, fp32-direct) + zeros (384) + W2/W3 splits (640)
    // + i8 quants (224) + rn1 (256)
    k_l1p<<<1568, 256, 0, stream>>>(x, W1, W2, W3, b1,
                                    dists, m1q, h1hi, h1lo,
                                    z2, outp, W2hi, W2lo, W3hi, W3lo,
                                    W1Ti8, saq, W2i8, sbq, W3i8, s3q, rn1);

    // l2a (128) || gemm1 (2048)
    k_big1<<<2176, 256, 0, stream>>>(h1hi, h1lo, W2hi, W2lo, z2,
                                     W1Ti8, W2i8, m1q, saq, sbq, qV2, norm2);

    // l3a z2-direct (32) || gemm2 mask-from-LDS (1024)
    k_big2<<<1056, 256, 0, stream>>>(z2, b2, W3hi, W3lo, z3,
                                     W3i8, qV2, saq, s3q, norm3);

    k_topk<<<B / 4, 256, 0, stream>>>(dists, rn1, z2, b2, norm2, z3, b3, norm3,
                                      kp, outp);
}